// Round 15
// baseline (137.285 us; speedup 1.0000x reference)
//
#include <hip/hip_runtime.h>

#define DM   1024
#define SEQ  2048
#define BATCH 2
#define NH   16
#define DHEAD 64
#define MTOT (BATCH*SEQ)   // 4096
#define KVB  64
#define EOFF ((size_t)MTOT * DM)
#define NROW (BATCH * NH * SEQ)   // 65536 head-rows

typedef _Float16 half_t;
typedef _Float16 half4 __attribute__((ext_vector_type(4)));
typedef _Float16 half8 __attribute__((ext_vector_type(8)));
typedef float    floatx4 __attribute__((ext_vector_type(4)));

#define SCALE2 0.18033688f   // (1/8) * log2(e)

__device__ __forceinline__ float fast_exp2(float x) {
  float r;
  asm volatile("v_exp_f32 %0, %1" : "=v"(r) : "v"(x));
  return r;
}

__device__ __forceinline__ void gload_lds16(const half_t* g, half_t* l) {
  __builtin_amdgcn_global_load_lds(
      (const __attribute__((address_space(1))) void*)g,
      (__attribute__((address_space(3))) void*)l, 16, 0, 0);
}

// ---------------- fused f32 -> f16 convert (all 7 arrays, one launch) ----------------
__global__ __launch_bounds__(256) void cvt_all(const float* __restrict__ q, const float* __restrict__ k,
                                               const float* __restrict__ v, const float* __restrict__ wq,
                                               const float* __restrict__ wk, const float* __restrict__ wv,
                                               const float* __restrict__ wo,
                                               half_t* __restrict__ dq, half_t* __restrict__ dk,
                                               half_t* __restrict__ dv, half_t* __restrict__ dwq,
                                               half_t* __restrict__ dwk, half_t* __restrict__ dwv,
                                               half_t* __restrict__ dwo) {
  const int y = blockIdx.y;
  const float* s; half_t* d; int n8;
  const int En8 = MTOT * DM / 8, Wn8 = DM * DM / 8;
  switch (y) {
    case 0: s = q;  d = dq;  n8 = En8; break;
    case 1: s = k;  d = dk;  n8 = En8; break;
    case 2: s = v;  d = dv;  n8 = En8; break;
    case 3: s = wq; d = dwq; n8 = Wn8; break;
    case 4: s = wk; d = dwk; n8 = Wn8; break;
    case 5: s = wv; d = dwv; n8 = Wn8; break;
    default: s = wo; d = dwo; n8 = Wn8; break;
  }
  int i = blockIdx.x * 256 + threadIdx.x;
  if (i >= n8) return;
  const float4* sp = reinterpret_cast<const float4*>(s);
  float4 u = sp[(size_t)i * 2], w = sp[(size_t)i * 2 + 1];
  half8 h;
  h[0] = (half_t)u.x; h[1] = (half_t)u.y; h[2] = (half_t)u.z; h[3] = (half_t)u.w;
  h[4] = (half_t)w.x; h[5] = (half_t)w.y; h[6] = (half_t)w.z; h[7] = (half_t)w.w;
  *reinterpret_cast<half8*>(d + (size_t)i * 8) = h;
}

// ---------------- QKV GEMM: m97 structure, 2D XCD chunking, swapped epilogue ---------
__global__ __launch_bounds__(256) void gemm_qkv(const half_t* __restrict__ Xq,
                                                const half_t* __restrict__ Xk,
                                                const half_t* __restrict__ Xv,
                                                const half_t* __restrict__ Wq,
                                                const half_t* __restrict__ Wk,
                                                const half_t* __restrict__ Wv,
                                                half_t* __restrict__ Qb,
                                                half_t* __restrict__ Kb,
                                                half_t* __restrict__ Vb) {
  __shared__ half_t As[2][128 * 32];
  __shared__ half_t Bs[2][128 * 32];
  const int which = blockIdx.x >> 8;
  const int flat = blockIdx.x & 255;
  const half_t* Ag = (which == 0) ? Xq : (which == 1) ? Xk : Xv;
  const half_t* Bg = (which == 0) ? Wq : (which == 1) ? Wk : Wv;
  half_t* Cg       = (which == 0) ? Qb : (which == 1) ? Kb : Vb;
  const float esc  = (which == 0) ? SCALE2 : 1.0f;

  const int tid = threadIdx.x, lane = tid & 63, w = tid >> 6;
  const int lr = lane & 15, lg = lane >> 4;
  const int xcd = flat & 7, bi = flat >> 3;
  const int m0 = (xcd * 4 + (bi >> 3)) * 128;
  const int n0 = (bi & 7) * 128;
  const int wm = (w >> 1) * 64, wn = (w & 1) * 64;
  floatx4 acc[4][4] = {};

  const half_t* aSrc[2]; const half_t* bSrc[2]; int dstOff[2];
#pragma unroll
  for (int j = 0; j < 2; j++) {
    int id = tid + j * 256;
    aSrc[j] = Ag + (size_t)(m0 + (id >> 2)) * DM + (id & 3) * 8;
    bSrc[j] = Bg + (size_t)(n0 + (id >> 2)) * DM + (id & 3) * 8;
    dstOff[j] = id * 8;
  }

#define STAGE_QKV(BUF, K0)                                                    \
  {                                                                           \
    _Pragma("unroll")                                                         \
    for (int j = 0; j < 2; j++) {                                             \
      gload_lds16(aSrc[j] + (K0), &As[BUF][dstOff[j]]);                       \
      gload_lds16(bSrc[j] + (K0), &Bs[BUF][dstOff[j]]);                       \
    }                                                                         \
  }
#define COMP_QKV(BUF)                                                         \
  {                                                                           \
    half8 a[4], b[4];                                                         \
    _Pragma("unroll")                                                         \
    for (int i = 0; i < 4; i++)                                               \
      a[i] = *reinterpret_cast<half8*>(&As[BUF][(wm + i * 16 + lr) * 32 + lg * 8]); \
    _Pragma("unroll")                                                         \
    for (int j = 0; j < 4; j++)                                               \
      b[j] = *reinterpret_cast<half8*>(&Bs[BUF][(wn + j * 16 + lr) * 32 + lg * 8]); \
    _Pragma("unroll")                                                         \
    for (int i = 0; i < 4; i++)                                               \
      _Pragma("unroll")                                                       \
      for (int j = 0; j < 4; j++)                                             \
        acc[i][j] = __builtin_amdgcn_mfma_f32_16x16x32_f16(b[j], a[i], acc[i][j], 0, 0, 0); \
  }

  STAGE_QKV(0, 0);
  __syncthreads();
  int buf = 0;
#pragma unroll 1
  for (int t = 0; t < 31; t++) {
    STAGE_QKV(buf ^ 1, (t + 1) * 32);
    COMP_QKV(buf);
    __syncthreads();
    buf ^= 1;
  }
  COMP_QKV(buf);

#pragma unroll
  for (int i = 0; i < 4; i++) {
    const int m = m0 + wm + i * 16 + lr;
    const int b_ = m >> 11, s_ = m & 2047;
#pragma unroll
    for (int j = 0; j < 4; j++) {
      const int n = n0 + wn + j * 16 + lg * 4;
      const int h_ = n >> 6, d_ = n & 63;
      half4 o;
#pragma unroll
      for (int r = 0; r < 4; r++) o[r] = (half_t)(acc[i][j][r] * esc);
      *reinterpret_cast<half4*>(
          &Cg[(((size_t)b_ * NH + h_) * SEQ + s_) * DHEAD + d_]) = o;
    }
  }
#undef STAGE_QKV
#undef COMP_QKV
}

// ---------------- O GEMM with fused split-K combine (f32 combine math) ---------------
__global__ __launch_bounds__(256) void gemm_o(const half_t* __restrict__ Pp,
                                              const float* __restrict__ Lp,
                                              const half_t* __restrict__ Bg,
                                              float* __restrict__ Cg) {
  __shared__ half_t As[2][128 * 32];
  __shared__ half_t Bs[2][64 * 32];
  const int tid = threadIdx.x, lane = tid & 63, w = tid >> 6;
  const int lr = lane & 15, lg = lane >> 4;
  const int flat = blockIdx.x;
  const int xcd = flat & 7, bi = flat >> 3;
  const int m0 = (xcd * 4 + (bi >> 4)) * 128;
  const int n0 = (bi & 15) * 64;
  const int wm = (w >> 1) * 64, wn = (w & 1) * 32;
  floatx4 acc[4][2] = {};

  size_t rowterm[2]; int col8[2], dst[2];
#pragma unroll
  for (int j = 0; j < 2; j++) {
    int id = tid + j * 256;
    int row = m0 + (id >> 2);
    col8[j] = (id & 3) * 8;
    dst[j] = id * 8;
    int b_ = row >> 11, s_ = row & 2047;
    rowterm[j] = (size_t)b_ * NH * SEQ + s_;
  }
  const half_t* bSrc = Bg + (size_t)(n0 + (tid >> 2)) * DM + (tid & 3) * 8;

  half8 p0r[2], p1r[2];
  float invv[2];

#define LOADP(K0)                                                             \
  {                                                                           \
    _Pragma("unroll")                                                         \
    for (int j = 0; j < 2; j++) {                                             \
      int k = (K0) + col8[j];                                                 \
      size_t lrow = rowterm[j] + (size_t)(k >> 6) * SEQ;                      \
      size_t pbase = lrow * 64 + (k & 63);                                    \
      p0r[j] = *reinterpret_cast<const half8*>(Pp + pbase);                   \
      p1r[j] = *reinterpret_cast<const half8*>(Pp + EOFF + pbase);            \
      invv[j] = 1.0f / (Lp[lrow] + Lp[NROW + lrow]);                          \
    }                                                                         \
  }
#define WRITEP(BUF)                                                           \
  {                                                                           \
    _Pragma("unroll")                                                         \
    for (int j = 0; j < 2; j++) {                                             \
      half8 o;                                                                \
      _Pragma("unroll")                                                       \
      for (int e = 0; e < 8; e++)                                             \
        o[e] = (half_t)(((float)p0r[j][e] + (float)p1r[j][e]) * invv[j]);     \
      *reinterpret_cast<half8*>(&As[BUF][dst[j]]) = o;                        \
    }                                                                         \
  }
#define COMP_O(BUF)                                                           \
  {                                                                           \
    half8 a[4], b[2];                                                         \
    _Pragma("unroll")                                                         \
    for (int i = 0; i < 4; i++)                                               \
      a[i] = *reinterpret_cast<half8*>(&As[BUF][(wm + i * 16 + lr) * 32 + lg * 8]); \
    _Pragma("unroll")                                                         \
    for (int j = 0; j < 2; j++)                                               \
      b[j] = *reinterpret_cast<half8*>(&Bs[BUF][(wn + j * 16 + lr) * 32 + lg * 8]); \
    _Pragma("unroll")                                                         \
    for (int i = 0; i < 4; i++)                                               \
      _Pragma("unroll")                                                       \
      for (int j = 0; j < 2; j++)                                             \
        acc[i][j] = __builtin_amdgcn_mfma_f32_16x16x32_f16(b[j], a[i], acc[i][j], 0, 0, 0); \
  }

  LOADP(0);
  gload_lds16(bSrc, &Bs[0][tid * 8]);
  WRITEP(0);
  __syncthreads();
  int buf = 0;
#pragma unroll 1
  for (int t = 0; t < 31; t++) {
    const int k0 = (t + 1) * 32;
    gload_lds16(bSrc + k0, &Bs[buf ^ 1][tid * 8]);   // async B, issue early
    LOADP(k0);                                        // P loads hide under compute
    COMP_O(buf);
    WRITEP(buf ^ 1);                                  // write-late (disjoint buffer)
    __syncthreads();
    buf ^= 1;
  }
  COMP_O(buf);

#pragma unroll
  for (int i = 0; i < 4; i++) {
    const int m = m0 + wm + i * 16 + lr;
#pragma unroll
    for (int j = 0; j < 2; j++) {
      const int n = n0 + wn + j * 16 + lg * 4;
      floatx4 o = acc[i][j];
      *reinterpret_cast<floatx4*>(&Cg[(size_t)m * DM + n]) = o;
    }
  }
#undef LOADP
#undef WRITEP
#undef COMP_O
}

// ---------------- causal flash attention v4 (round-12 proven, KVB=64) ---------------
// 1024 blocks x 512 threads (8 waves, 128 q-rows/block), split-K x2 over 64-kv tiles.
// Swapped QK^T; P in registers via matched k-slot permutation. No-max softmax;
// lsum via ones-column MFMA tile; heavy-first dispatch, per-XCD (b,h) clustering.
__global__ __launch_bounds__(512) void attn_fwd(const half_t* __restrict__ Q,
                                                const half_t* __restrict__ K,
                                                const half_t* __restrict__ V,
                                                half_t* __restrict__ P,
                                                float* __restrict__ L) {
  __shared__ half_t Ks[64][72];
  __shared__ half_t Vt[80][72];        // rows 0..63 V^T; 64 ones; 65..79 zero
  const int tid = threadIdx.x, lane = tid & 63, w = tid >> 6;
  const int lr = lane & 15, lg = lane >> 4;

  const int flat = blockIdx.x;               // 0..1023
  const int xcd = flat & 7, idx = flat >> 3; // 0..127
  const int qblk = 15 - (idx >> 3);          // heavy first, 128-row q-blocks
  const int sub = idx & 7;
  const int combo = xcd * 4 + (sub >> 1);
  const int split = sub & 1;
  const int h = combo & 15, b = combo >> 4;

  const size_t bh = ((size_t)b * NH + h) * SEQ * DHEAD;
  const int q0 = qblk * 128 + w * 16;        // wave's 16 q-rows
  const int nt = 2 * (qblk + 1);
  const int h0 = qblk + 1;
  const int t0 = split ? h0 : 0;
  const int t1 = split ? nt : h0;

  for (int i2 = tid; i2 < 16 * 72; i2 += 512) {
    int d = i2 / 72, kv = i2 % 72;
    Vt[64 + d][kv] = (d == 0) ? (half_t)1.0f : (half_t)0.0f;
  }

  half8 qf[2];
#pragma unroll
  for (int ks = 0; ks < 2; ks++)
    qf[ks] = *reinterpret_cast<const half8*>(
        Q + bh + (size_t)(q0 + lr) * DHEAD + ks * 32 + lg * 8);

  floatx4 accO[5] = {};   // j<4: O[d rows][q cols]; j=4: row-sum tile

  half8 kr, vr;
#define LOADT(t)                                                              \
  {                                                                           \
    const int kvb2 = (t) * KVB;                                               \
    kr = *reinterpret_cast<const half8*>(                                     \
        K + bh + (size_t)(kvb2 + (tid >> 3)) * DHEAD + (tid & 7) * 8);        \
    vr = *reinterpret_cast<const half8*>(                                     \
        V + bh + (size_t)(kvb2 + (tid & 63)) * DHEAD + (tid >> 6) * 8);       \
  }
#define WRITET()                                                              \
  {                                                                           \
    *reinterpret_cast<half8*>(&Ks[tid >> 3][(tid & 7) * 8]) = kr;             \
    int vrow = tid & 63, vcol = (tid >> 6) * 8;                               \
    _Pragma("unroll")                                                         \
    for (int e = 0; e < 8; e++) Vt[vcol + e][vrow] = vr[e];                   \
  }

  LOADT(t0);
  WRITET();
  __syncthreads();

#pragma unroll 1
  for (int t = t0; t < t1; t++) {
    const int kvbase = t * KVB;
    if (t + 1 < t1) LOADT(t + 1);
    if (kvbase <= q0 + 15) {                 // wave has visible kv in this tile
      const bool need_mask = (kvbase + KVB - 1) > q0;
      // S^T = K Q^T : lane holds q=lr, kv = jt*16 + lg*4 + r
      floatx4 s[4];
#pragma unroll
      for (int jt = 0; jt < 4; jt++) {
        floatx4 a0 = {};
#pragma unroll
        for (int ks = 0; ks < 2; ks++) {
          half8 ak = *reinterpret_cast<half8*>(&Ks[jt * 16 + lr][ks * 32 + lg * 8]);
          a0 = __builtin_amdgcn_mfma_f32_16x16x32_f16(ak, qf[ks], a0, 0, 0, 0);
        }
        s[jt] = a0;
      }
      const int qq = q0 + lr;
#pragma unroll
      for (int jt = 0; jt < 4; jt++)
#pragma unroll
        for (int r = 0; r < 4; r++) {
          float pp = fast_exp2(s[jt][r]);
          if (need_mask) {
            int kv = kvbase + jt * 16 + lg * 4 + r;
            if (kv > qq) pp = 0.f;
          }
          s[jt][r] = pp;
        }
      // P B-fragments straight from registers (k-slot perm):
      half8 pb[2];
#pragma unroll
      for (int ks = 0; ks < 2; ks++) {
#pragma unroll
        for (int e = 0; e < 4; e++) {
          pb[ks][e]     = (half_t)s[2 * ks][e];
          pb[ks][4 + e] = (half_t)s[2 * ks + 1][e];
        }
      }
      // PV: A = V^T fragments in the SAME permuted kv order (2x b64 each)
#pragma unroll
      for (int j = 0; j < 5; j++) {
#pragma unroll
        for (int ks = 0; ks < 2; ks++) {
          half4 x = *reinterpret_cast<half4*>(&Vt[j * 16 + lr][ks * 32 + lg * 4]);
          half4 y = *reinterpret_cast<half4*>(&Vt[j * 16 + lr][ks * 32 + 16 + lg * 4]);
          half8 av;
          av[0] = x[0]; av[1] = x[1]; av[2] = x[2]; av[3] = x[3];
          av[4] = y[0]; av[5] = y[1]; av[6] = y[2]; av[7] = y[3];
          accO[j] = __builtin_amdgcn_mfma_f32_16x16x32_f16(av, pb[ks], accO[j], 0, 0, 0);
        }
      }
    }
    if (t + 1 < t1) {
      __syncthreads();
      WRITET();
      __syncthreads();
    }
  }

  // epilogue: lane holds q = q0+lr, d = j*16 + lg*4 + r -> half4 stores
  half_t* Pw = P + (size_t)split * EOFF;
  float*  Lw = L + (size_t)split * NROW;
  {
    const int q = q0 + lr;
    const size_t rowbase = bh + (size_t)q * DHEAD;
#pragma unroll
    for (int j = 0; j < 4; j++) {
      half4 o;
#pragma unroll
      for (int r = 0; r < 4; r++) o[r] = (half_t)accO[j][r];
      *reinterpret_cast<half4*>(&Pw[rowbase + j * 16 + lg * 4]) = o;
    }
    if (lg == 0)
      Lw[((size_t)b * NH + h) * SEQ + q] = accO[4][0];
  }
#undef LOADT
#undef WRITET
}

extern "C" void kernel_launch(void* const* d_in, const int* in_sizes, int n_in,
                              void* d_out, int out_size, void* d_ws, size_t ws_size,
                              hipStream_t stream) {
  const float* q_in = (const float*)d_in[0];
  const float* k_in = (const float*)d_in[1];
  const float* v_in = (const float*)d_in[2];
  const float* Wq   = (const float*)d_in[5];
  const float* Wk   = (const float*)d_in[6];
  const float* Wv   = (const float*)d_in[7];
  const float* Wo   = (const float*)d_in[8];

  const size_t E = EOFF;
  const size_t W = (size_t)DM * DM;
  half_t* ws  = (half_t*)d_ws;
  half_t* Xq  = ws;
  half_t* Xk  = ws + E;         // cvt X_k; later: attn partial P (2E)
  half_t* Xv  = ws + 2 * E;
  half_t* Wqh = ws + 3 * E;     // f16 Wq; later: attn partial L (2 x 256KB)
  half_t* Wkh = Wqh + W;
  half_t* Wvh = Wkh + W;
  half_t* Woh = Wvh + W;
  half_t* Qb  = ws + 4 * E;
  half_t* Kb  = ws + 5 * E;
  half_t* Vb  = ws + 6 * E;
  half_t* Pp  = Xk;             // partial O, [2][B][H][S][64]
  float*  Lp  = (float*)Wqh;    // partial sums, [2][NROW]
  if (ws_size < 7 * E * sizeof(half_t)) return;

  cvt_all<<<dim3(2048, 7), 256, 0, stream>>>(q_in, k_in, v_in, Wq, Wk, Wv, Wo,
                                             Xq, Xk, Xv, Wqh, Wkh, Wvh, Woh);
  gemm_qkv<<<768, 256, 0, stream>>>(Xq, Xk, Xv, Wqh, Wkh, Wvh, Qb, Kb, Vb);
  attn_fwd<<<1024, 512, 0, stream>>>(Qb, Kb, Vb, Pp, Lp);
  gemm_o<<<512, 256, 0, stream>>>(Pp, Lp, Woh, (float*)d_out);
}

// Round 16
// 134.499 us; speedup vs baseline: 1.0207x; 1.0207x over previous
//
#include <hip/hip_runtime.h>

#define DM   1024
#define SEQ  2048
#define BATCH 2
#define NH   16
#define DHEAD 64
#define MTOT (BATCH*SEQ)   // 4096
#define KVB  64
#define EOFF ((size_t)MTOT * DM)
#define NROW (BATCH * NH * SEQ)   // 65536 head-rows

typedef _Float16 half_t;
typedef _Float16 half4 __attribute__((ext_vector_type(4)));
typedef _Float16 half8 __attribute__((ext_vector_type(8)));
typedef float    floatx4 __attribute__((ext_vector_type(4)));

#define SCALE2 0.18033688f   // (1/8) * log2(e)

__device__ __forceinline__ float fast_exp2(float x) {
  float r;
  asm volatile("v_exp_f32 %0, %1" : "=v"(r) : "v"(x));
  return r;
}

__device__ __forceinline__ void gload_lds16(const half_t* g, half_t* l) {
  __builtin_amdgcn_global_load_lds(
      (const __attribute__((address_space(1))) void*)g,
      (__attribute__((address_space(3))) void*)l, 16, 0, 0);
}

// ---------------- fused f32 -> f16 convert (all 7 arrays, one launch) ----------------
__global__ __launch_bounds__(256) void cvt_all(const float* __restrict__ q, const float* __restrict__ k,
                                               const float* __restrict__ v, const float* __restrict__ wq,
                                               const float* __restrict__ wk, const float* __restrict__ wv,
                                               const float* __restrict__ wo,
                                               half_t* __restrict__ dq, half_t* __restrict__ dk,
                                               half_t* __restrict__ dv, half_t* __restrict__ dwq,
                                               half_t* __restrict__ dwk, half_t* __restrict__ dwv,
                                               half_t* __restrict__ dwo) {
  const int y = blockIdx.y;
  const float* s; half_t* d; int n8;
  const int En8 = MTOT * DM / 8, Wn8 = DM * DM / 8;
  switch (y) {
    case 0: s = q;  d = dq;  n8 = En8; break;
    case 1: s = k;  d = dk;  n8 = En8; break;
    case 2: s = v;  d = dv;  n8 = En8; break;
    case 3: s = wq; d = dwq; n8 = Wn8; break;
    case 4: s = wk; d = dwk; n8 = Wn8; break;
    case 5: s = wv; d = dwv; n8 = Wn8; break;
    default: s = wo; d = dwo; n8 = Wn8; break;
  }
  int i = blockIdx.x * 256 + threadIdx.x;
  if (i >= n8) return;
  const float4* sp = reinterpret_cast<const float4*>(s);
  float4 u = sp[(size_t)i * 2], w = sp[(size_t)i * 2 + 1];
  half8 h;
  h[0] = (half_t)u.x; h[1] = (half_t)u.y; h[2] = (half_t)u.z; h[3] = (half_t)u.w;
  h[4] = (half_t)w.x; h[5] = (half_t)w.y; h[6] = (half_t)w.z; h[7] = (half_t)w.w;
  *reinterpret_cast<half8*>(d + (size_t)i * 8) = h;
}

// ---------------- QKV GEMM: BM=128, BN=64, BK=32 (24 KB LDS -> 6 blocks/CU) ----------
// grid 1536 = 3 x 512; 2D XCD chunking (4 m-tiles x 16 n-tiles per XCD).
// Each block covers exactly one head (BN=64). Q output pre-scaled by SCALE2.
__global__ __launch_bounds__(256) void gemm_qkv(const half_t* __restrict__ Xq,
                                                const half_t* __restrict__ Xk,
                                                const half_t* __restrict__ Xv,
                                                const half_t* __restrict__ Wq,
                                                const half_t* __restrict__ Wk,
                                                const half_t* __restrict__ Wv,
                                                half_t* __restrict__ Qb,
                                                half_t* __restrict__ Kb,
                                                half_t* __restrict__ Vb) {
  __shared__ half_t As[2][128 * 32];
  __shared__ half_t Bs[2][64 * 32];
  const int which = blockIdx.x >> 9;
  const int flat = blockIdx.x & 511;
  const half_t* Ag = (which == 0) ? Xq : (which == 1) ? Xk : Xv;
  const half_t* Bg = (which == 0) ? Wq : (which == 1) ? Wk : Wv;
  half_t* Cg       = (which == 0) ? Qb : (which == 1) ? Kb : Vb;
  const float esc  = (which == 0) ? SCALE2 : 1.0f;

  const int tid = threadIdx.x, lane = tid & 63, w = tid >> 6;
  const int lr = lane & 15, lg = lane >> 4;
  const int xcd = flat & 7, bi = flat >> 3;        // bi 0..63
  const int m0 = (xcd * 4 + (bi >> 4)) * 128;      // 4 m-tiles per XCD
  const int n0 = (bi & 15) * 64;                   // all 16 n-tiles per XCD
  const int wm = (w >> 1) * 64, wn = (w & 1) * 32;
  floatx4 acc[4][2] = {};

  const half_t* aSrc[2]; int dstOff[2];
#pragma unroll
  for (int j = 0; j < 2; j++) {
    int id = tid + j * 256;
    aSrc[j] = Ag + (size_t)(m0 + (id >> 2)) * DM + (id & 3) * 8;
    dstOff[j] = id * 8;
  }
  const half_t* bSrc = Bg + (size_t)(n0 + (tid >> 2)) * DM + (tid & 3) * 8;

#define STAGE_QKV(BUF, K0)                                                    \
  {                                                                           \
    _Pragma("unroll")                                                         \
    for (int j = 0; j < 2; j++)                                               \
      gload_lds16(aSrc[j] + (K0), &As[BUF][dstOff[j]]);                       \
    gload_lds16(bSrc + (K0), &Bs[BUF][tid * 8]);                              \
  }
#define COMP_QKV(BUF)                                                         \
  {                                                                           \
    half8 a[4], b[2];                                                         \
    _Pragma("unroll")                                                         \
    for (int i = 0; i < 4; i++)                                               \
      a[i] = *reinterpret_cast<half8*>(&As[BUF][(wm + i * 16 + lr) * 32 + lg * 8]); \
    _Pragma("unroll")                                                         \
    for (int j = 0; j < 2; j++)                                               \
      b[j] = *reinterpret_cast<half8*>(&Bs[BUF][(wn + j * 16 + lr) * 32 + lg * 8]); \
    _Pragma("unroll")                                                         \
    for (int i = 0; i < 4; i++)                                               \
      _Pragma("unroll")                                                       \
      for (int j = 0; j < 2; j++)                                             \
        acc[i][j] = __builtin_amdgcn_mfma_f32_16x16x32_f16(b[j], a[i], acc[i][j], 0, 0, 0); \
  }

  STAGE_QKV(0, 0);
  __syncthreads();
  int buf = 0;
#pragma unroll 1
  for (int t = 0; t < 31; t++) {
    STAGE_QKV(buf ^ 1, (t + 1) * 32);
    COMP_QKV(buf);
    __syncthreads();
    buf ^= 1;
  }
  COMP_QKV(buf);

  // epilogue: lane holds 4 consecutive n (row axis), fixed m (col = lr)
  const int h_ = n0 >> 6;                          // one head per block
#pragma unroll
  for (int i = 0; i < 4; i++) {
    const int m = m0 + wm + i * 16 + lr;
    const int b_ = m >> 11, s_ = m & 2047;
#pragma unroll
    for (int j = 0; j < 2; j++) {
      const int d_ = wn + j * 16 + lg * 4;
      half4 o;
#pragma unroll
      for (int r = 0; r < 4; r++) o[r] = (half_t)(acc[i][j][r] * esc);
      *reinterpret_cast<half4*>(
          &Cg[(((size_t)b_ * NH + h_) * SEQ + s_) * DHEAD + d_]) = o;
    }
  }
#undef STAGE_QKV
#undef COMP_QKV
}

// ---------------- O GEMM: BM=128, BN=64, BK=32, grid 512, 2D XCD chunking ------------
__global__ __launch_bounds__(256) void gemm_o(const half_t* __restrict__ Ag,
                                              const half_t* __restrict__ Bg,
                                              float* __restrict__ Cg) {
  __shared__ half_t As[2][128 * 32];
  __shared__ half_t Bs[2][64 * 32];
  const int tid = threadIdx.x, lane = tid & 63, w = tid >> 6;
  const int lr = lane & 15, lg = lane >> 4;
  const int flat = blockIdx.x;
  const int xcd = flat & 7, bi = flat >> 3;
  const int m0 = (xcd * 4 + (bi >> 4)) * 128;
  const int n0 = (bi & 15) * 64;
  const int wm = (w >> 1) * 64, wn = (w & 1) * 32;
  floatx4 acc[4][2] = {};

  const half_t* aSrc[2]; int dstOff[2];
#pragma unroll
  for (int j = 0; j < 2; j++) {
    int id = tid + j * 256;
    aSrc[j] = Ag + (size_t)(m0 + (id >> 2)) * DM + (id & 3) * 8;
    dstOff[j] = id * 8;
  }
  const half_t* bSrc = Bg + (size_t)(n0 + (tid >> 2)) * DM + (tid & 3) * 8;

#define STAGE_O(BUF, K0)                                                      \
  {                                                                           \
    _Pragma("unroll")                                                         \
    for (int j = 0; j < 2; j++)                                               \
      gload_lds16(aSrc[j] + (K0), &As[BUF][dstOff[j]]);                       \
    gload_lds16(bSrc + (K0), &Bs[BUF][tid * 8]);                              \
  }
#define COMP_O(BUF)                                                           \
  {                                                                           \
    half8 a[4], b[2];                                                         \
    _Pragma("unroll")                                                         \
    for (int i = 0; i < 4; i++)                                               \
      a[i] = *reinterpret_cast<half8*>(&As[BUF][(wm + i * 16 + lr) * 32 + lg * 8]); \
    _Pragma("unroll")                                                         \
    for (int j = 0; j < 2; j++)                                               \
      b[j] = *reinterpret_cast<half8*>(&Bs[BUF][(wn + j * 16 + lr) * 32 + lg * 8]); \
    _Pragma("unroll")                                                         \
    for (int i = 0; i < 4; i++)                                               \
      _Pragma("unroll")                                                       \
      for (int j = 0; j < 2; j++)                                             \
        acc[i][j] = __builtin_amdgcn_mfma_f32_16x16x32_f16(b[j], a[i], acc[i][j], 0, 0, 0); \
  }

  STAGE_O(0, 0);
  __syncthreads();
  int buf = 0;
#pragma unroll 1
  for (int t = 0; t < 31; t++) {
    STAGE_O(buf ^ 1, (t + 1) * 32);
    COMP_O(buf);
    __syncthreads();
    buf ^= 1;
  }
  COMP_O(buf);

#pragma unroll
  for (int i = 0; i < 4; i++) {
    const int m = m0 + wm + i * 16 + lr;
#pragma unroll
    for (int j = 0; j < 2; j++) {
      const int n = n0 + wn + j * 16 + lg * 4;
      floatx4 o = acc[i][j];
      *reinterpret_cast<floatx4*>(&Cg[(size_t)m * DM + n]) = o;
    }
  }
#undef STAGE_O
#undef COMP_O
}

// ---------------- causal flash attention v4 (round-12 proven, KVB=64) ---------------
__global__ __launch_bounds__(512) void attn_fwd(const half_t* __restrict__ Q,
                                                const half_t* __restrict__ K,
                                                const half_t* __restrict__ V,
                                                half_t* __restrict__ P,
                                                float* __restrict__ L) {
  __shared__ half_t Ks[64][72];
  __shared__ half_t Vt[80][72];        // rows 0..63 V^T; 64 ones; 65..79 zero
  const int tid = threadIdx.x, lane = tid & 63, w = tid >> 6;
  const int lr = lane & 15, lg = lane >> 4;

  const int flat = blockIdx.x;               // 0..1023
  const int xcd = flat & 7, idx = flat >> 3; // 0..127
  const int qblk = 15 - (idx >> 3);          // heavy first, 128-row q-blocks
  const int sub = idx & 7;
  const int combo = xcd * 4 + (sub >> 1);
  const int split = sub & 1;
  const int h = combo & 15, b = combo >> 4;

  const size_t bh = ((size_t)b * NH + h) * SEQ * DHEAD;
  const int q0 = qblk * 128 + w * 16;        // wave's 16 q-rows
  const int nt = 2 * (qblk + 1);
  const int h0 = qblk + 1;
  const int t0 = split ? h0 : 0;
  const int t1 = split ? nt : h0;

  for (int i2 = tid; i2 < 16 * 72; i2 += 512) {
    int d = i2 / 72, kv = i2 % 72;
    Vt[64 + d][kv] = (d == 0) ? (half_t)1.0f : (half_t)0.0f;
  }

  half8 qf[2];
#pragma unroll
  for (int ks = 0; ks < 2; ks++)
    qf[ks] = *reinterpret_cast<const half8*>(
        Q + bh + (size_t)(q0 + lr) * DHEAD + ks * 32 + lg * 8);

  floatx4 accO[5] = {};   // j<4: O[d rows][q cols]; j=4: row-sum tile

  half8 kr, vr;
#define LOADT(t)                                                              \
  {                                                                           \
    const int kvb2 = (t) * KVB;                                               \
    kr = *reinterpret_cast<const half8*>(                                     \
        K + bh + (size_t)(kvb2 + (tid >> 3)) * DHEAD + (tid & 7) * 8);        \
    vr = *reinterpret_cast<const half8*>(                                     \
        V + bh + (size_t)(kvb2 + (tid & 63)) * DHEAD + (tid >> 6) * 8);       \
  }
#define WRITET()                                                              \
  {                                                                           \
    *reinterpret_cast<half8*>(&Ks[tid >> 3][(tid & 7) * 8]) = kr;             \
    int vrow = tid & 63, vcol = (tid >> 6) * 8;                               \
    _Pragma("unroll")                                                         \
    for (int e = 0; e < 8; e++) Vt[vcol + e][vrow] = vr[e];                   \
  }

  LOADT(t0);
  WRITET();
  __syncthreads();

#pragma unroll 1
  for (int t = t0; t < t1; t++) {
    const int kvbase = t * KVB;
    if (t + 1 < t1) LOADT(t + 1);
    if (kvbase <= q0 + 15) {                 // wave has visible kv in this tile
      const bool need_mask = (kvbase + KVB - 1) > q0;
      // S^T = K Q^T : lane holds q=lr, kv = jt*16 + lg*4 + r
      floatx4 s[4];
#pragma unroll
      for (int jt = 0; jt < 4; jt++) {
        floatx4 a0 = {};
#pragma unroll
        for (int ks = 0; ks < 2; ks++) {
          half8 ak = *reinterpret_cast<half8*>(&Ks[jt * 16 + lr][ks * 32 + lg * 8]);
          a0 = __builtin_amdgcn_mfma_f32_16x16x32_f16(ak, qf[ks], a0, 0, 0, 0);
        }
        s[jt] = a0;
      }
      const int qq = q0 + lr;
#pragma unroll
      for (int jt = 0; jt < 4; jt++)
#pragma unroll
        for (int r = 0; r < 4; r++) {
          float pp = fast_exp2(s[jt][r]);
          if (need_mask) {
            int kv = kvbase + jt * 16 + lg * 4 + r;
            if (kv > qq) pp = 0.f;
          }
          s[jt][r] = pp;
        }
      // P B-fragments straight from registers (k-slot perm):
      half8 pb[2];
#pragma unroll
      for (int ks = 0; ks < 2; ks++) {
#pragma unroll
        for (int e = 0; e < 4; e++) {
          pb[ks][e]     = (half_t)s[2 * ks][e];
          pb[ks][4 + e] = (half_t)s[2 * ks + 1][e];
        }
      }
      // PV: A = V^T fragments in the SAME permuted kv order (2x b64 each)
#pragma unroll
      for (int j = 0; j < 5; j++) {
#pragma unroll
        for (int ks = 0; ks < 2; ks++) {
          half4 x = *reinterpret_cast<half4*>(&Vt[j * 16 + lr][ks * 32 + lg * 4]);
          half4 y = *reinterpret_cast<half4*>(&Vt[j * 16 + lr][ks * 32 + 16 + lg * 4]);
          half8 av;
          av[0] = x[0]; av[1] = x[1]; av[2] = x[2]; av[3] = x[3];
          av[4] = y[0]; av[5] = y[1]; av[6] = y[2]; av[7] = y[3];
          accO[j] = __builtin_amdgcn_mfma_f32_16x16x32_f16(av, pb[ks], accO[j], 0, 0, 0);
        }
      }
    }
    if (t + 1 < t1) {
      __syncthreads();
      WRITET();
      __syncthreads();
    }
  }

  // epilogue: lane holds q = q0+lr, d = j*16 + lg*4 + r -> half4 stores
  half_t* Pw = P + (size_t)split * EOFF;
  float*  Lw = L + (size_t)split * NROW;
  {
    const int q = q0 + lr;
    const size_t rowbase = bh + (size_t)q * DHEAD;
#pragma unroll
    for (int j = 0; j < 4; j++) {
      half4 o;
#pragma unroll
      for (int r = 0; r < 4; r++) o[r] = (half_t)accO[j][r];
      *reinterpret_cast<half4*>(&Pw[rowbase + j * 16 + lg * 4]) = o;
    }
    if (lg == 0)
      Lw[((size_t)b * NH + h) * SEQ + q] = accO[4][0];
  }
#undef LOADT
#undef WRITET
}

// ---------------- combine: O = (P0 + P1) / (l0 + l1), scatter heads -> [B][S][DM] ----
__global__ __launch_bounds__(256) void attn_combine(const half_t* __restrict__ P,
                                                    const float* __restrict__ L,
                                                    half_t* __restrict__ Ab) {
  size_t i = (size_t)blockIdx.x * 256 + threadIdx.x;   // chunk of 8, total E/8
  half8 p0 = *reinterpret_cast<const half8*>(P + i * 8);
  half8 p1 = *reinterpret_cast<const half8*>(P + EOFF + i * 8);
  size_t row = i >> 3;                 // [b][h][s]
  float l = L[row] + L[NROW + row];
  float inv = 1.0f / l;
  int s_ = (int)(row % SEQ);
  int h_ = (int)((row / SEQ) % NH);
  int b_ = (int)(row / ((size_t)SEQ * NH));
  int d0 = (int)(i & 7) * 8;
  half8 o;
#pragma unroll
  for (int e = 0; e < 8; e++)
    o[e] = (half_t)(((float)p0[e] + (float)p1[e]) * inv);
  *reinterpret_cast<half8*>(Ab + ((size_t)b_ * SEQ + s_) * DM + h_ * DHEAD + d0) = o;
}

extern "C" void kernel_launch(void* const* d_in, const int* in_sizes, int n_in,
                              void* d_out, int out_size, void* d_ws, size_t ws_size,
                              hipStream_t stream) {
  const float* q_in = (const float*)d_in[0];
  const float* k_in = (const float*)d_in[1];
  const float* v_in = (const float*)d_in[2];
  const float* Wq   = (const float*)d_in[5];
  const float* Wk   = (const float*)d_in[6];
  const float* Wv   = (const float*)d_in[7];
  const float* Wo   = (const float*)d_in[8];

  const size_t E = EOFF;
  const size_t W = (size_t)DM * DM;
  half_t* ws  = (half_t*)d_ws;
  half_t* Xq  = ws;             // cvt X_q; later: combine output Ab
  half_t* Xk  = ws + E;         // cvt X_k; later: attn partial P (2E)
  half_t* Xv  = ws + 2 * E;
  half_t* Wqh = ws + 3 * E;     // f16 Wq; later: attn partial L (2 x 256KB)
  half_t* Wkh = Wqh + W;
  half_t* Wvh = Wkh + W;
  half_t* Woh = Wvh + W;
  half_t* Qb  = ws + 4 * E;
  half_t* Kb  = ws + 5 * E;
  half_t* Vb  = ws + 6 * E;
  half_t* Ab  = Xq;
  half_t* Pp  = Xk;             // partial O, [2][B][H][S][64]
  float*  Lp  = (float*)Wqh;    // partial sums, [2][NROW]
  if (ws_size < 7 * E * sizeof(half_t)) return;

  cvt_all<<<dim3(2048, 7), 256, 0, stream>>>(q_in, k_in, v_in, Wq, Wk, Wv, Wo,
                                             Xq, Xk, Xv, Wqh, Wkh, Wvh, Woh);
  gemm_qkv<<<1536, 256, 0, stream>>>(Xq, Xk, Xv, Wqh, Wkh, Wvh, Qb, Kb, Vb);
  attn_fwd<<<1024, 512, 0, stream>>>(Qb, Kb, Vb, Pp, Lp);
  attn_combine<<<2048, 256, 0, stream>>>(Pp, Lp, Ab);
  gemm_o<<<512, 256, 0, stream>>>(Ab, Woh, (float*)d_out);
}

// Round 17
// 128.367 us; speedup vs baseline: 1.0695x; 1.0478x over previous
//
#include <hip/hip_runtime.h>

#define DM   1024
#define SEQ  2048
#define BATCH 2
#define NH   16
#define DHEAD 64
#define MTOT (BATCH*SEQ)   // 4096
#define KVB  64
#define EOFF ((size_t)MTOT * DM)
#define NROW (BATCH * NH * SEQ)   // 65536 head-rows

typedef _Float16 half_t;
typedef _Float16 half4 __attribute__((ext_vector_type(4)));
typedef _Float16 half8 __attribute__((ext_vector_type(8)));
typedef float    floatx4 __attribute__((ext_vector_type(4)));

#define SCALE2 0.18033688f   // (1/8) * log2(e)

__device__ __forceinline__ float fast_exp2(float x) {
  float r;
  asm volatile("v_exp_f32 %0, %1" : "=v"(r) : "v"(x));
  return r;
}

__device__ __forceinline__ void gload_lds16(const half_t* g, half_t* l) {
  __builtin_amdgcn_global_load_lds(
      (const __attribute__((address_space(1))) void*)g,
      (__attribute__((address_space(3))) void*)l, 16, 0, 0);
}

// ---------------- fused f32 -> f16 convert (all 7 arrays, one launch) ----------------
__global__ __launch_bounds__(256) void cvt_all(const float* __restrict__ q, const float* __restrict__ k,
                                               const float* __restrict__ v, const float* __restrict__ wq,
                                               const float* __restrict__ wk, const float* __restrict__ wv,
                                               const float* __restrict__ wo,
                                               half_t* __restrict__ dq, half_t* __restrict__ dk,
                                               half_t* __restrict__ dv, half_t* __restrict__ dwq,
                                               half_t* __restrict__ dwk, half_t* __restrict__ dwv,
                                               half_t* __restrict__ dwo) {
  const int y = blockIdx.y;
  const float* s; half_t* d; int n8;
  const int En8 = MTOT * DM / 8, Wn8 = DM * DM / 8;
  switch (y) {
    case 0: s = q;  d = dq;  n8 = En8; break;
    case 1: s = k;  d = dk;  n8 = En8; break;
    case 2: s = v;  d = dv;  n8 = En8; break;
    case 3: s = wq; d = dwq; n8 = Wn8; break;
    case 4: s = wk; d = dwk; n8 = Wn8; break;
    case 5: s = wv; d = dwv; n8 = Wn8; break;
    default: s = wo; d = dwo; n8 = Wn8; break;
  }
  int i = blockIdx.x * 256 + threadIdx.x;
  if (i >= n8) return;
  const float4* sp = reinterpret_cast<const float4*>(s);
  float4 u = sp[(size_t)i * 2], w = sp[(size_t)i * 2 + 1];
  half8 h;
  h[0] = (half_t)u.x; h[1] = (half_t)u.y; h[2] = (half_t)u.z; h[3] = (half_t)u.w;
  h[4] = (half_t)w.x; h[5] = (half_t)w.y; h[6] = (half_t)w.z; h[7] = (half_t)w.w;
  *reinterpret_cast<half8*>(d + (size_t)i * 8) = h;
}

// ---------------- QKV GEMM: m97 structure, 2D XCD chunking, swapped epilogue ---------
// grid 768 = 3 x 256. Per XCD: 4 m-tiles x 8 n-tiles (A 1MB + B 2MB L2-resident).
__global__ __launch_bounds__(256) void gemm_qkv(const half_t* __restrict__ Xq,
                                                const half_t* __restrict__ Xk,
                                                const half_t* __restrict__ Xv,
                                                const half_t* __restrict__ Wq,
                                                const half_t* __restrict__ Wk,
                                                const half_t* __restrict__ Wv,
                                                half_t* __restrict__ Qb,
                                                half_t* __restrict__ Kb,
                                                half_t* __restrict__ Vb) {
  __shared__ half_t As[2][128 * 32];
  __shared__ half_t Bs[2][128 * 32];
  const int which = blockIdx.x >> 8;
  const int flat = blockIdx.x & 255;
  const half_t* Ag = (which == 0) ? Xq : (which == 1) ? Xk : Xv;
  const half_t* Bg = (which == 0) ? Wq : (which == 1) ? Wk : Wv;
  half_t* Cg       = (which == 0) ? Qb : (which == 1) ? Kb : Vb;
  const float esc  = (which == 0) ? SCALE2 : 1.0f;

  const int tid = threadIdx.x, lane = tid & 63, w = tid >> 6;
  const int lr = lane & 15, lg = lane >> 4;
  const int xcd = flat & 7, bi = flat >> 3;
  const int m0 = (xcd * 4 + (bi >> 3)) * 128;
  const int n0 = (bi & 7) * 128;
  const int wm = (w >> 1) * 64, wn = (w & 1) * 64;
  floatx4 acc[4][4] = {};

  const half_t* aSrc[2]; const half_t* bSrc[2]; int dstOff[2];
#pragma unroll
  for (int j = 0; j < 2; j++) {
    int id = tid + j * 256;
    aSrc[j] = Ag + (size_t)(m0 + (id >> 2)) * DM + (id & 3) * 8;
    bSrc[j] = Bg + (size_t)(n0 + (id >> 2)) * DM + (id & 3) * 8;
    dstOff[j] = id * 8;
  }

#define STAGE_QKV(BUF, K0)                                                    \
  {                                                                           \
    _Pragma("unroll")                                                         \
    for (int j = 0; j < 2; j++) {                                             \
      gload_lds16(aSrc[j] + (K0), &As[BUF][dstOff[j]]);                       \
      gload_lds16(bSrc[j] + (K0), &Bs[BUF][dstOff[j]]);                       \
    }                                                                         \
  }
#define COMP_QKV(BUF)                                                         \
  {                                                                           \
    half8 a[4], b[4];                                                         \
    _Pragma("unroll")                                                         \
    for (int i = 0; i < 4; i++)                                               \
      a[i] = *reinterpret_cast<half8*>(&As[BUF][(wm + i * 16 + lr) * 32 + lg * 8]); \
    _Pragma("unroll")                                                         \
    for (int j = 0; j < 4; j++)                                               \
      b[j] = *reinterpret_cast<half8*>(&Bs[BUF][(wn + j * 16 + lr) * 32 + lg * 8]); \
    _Pragma("unroll")                                                         \
    for (int i = 0; i < 4; i++)                                               \
      _Pragma("unroll")                                                       \
      for (int j = 0; j < 4; j++)                                             \
        acc[i][j] = __builtin_amdgcn_mfma_f32_16x16x32_f16(b[j], a[i], acc[i][j], 0, 0, 0); \
  }

  STAGE_QKV(0, 0);
  __syncthreads();
  int buf = 0;
#pragma unroll 1
  for (int t = 0; t < 31; t++) {
    STAGE_QKV(buf ^ 1, (t + 1) * 32);
    COMP_QKV(buf);
    __syncthreads();
    buf ^= 1;
  }
  COMP_QKV(buf);

  // epilogue: lane holds 4 consecutive n (row axis), fixed m (col = lr)
#pragma unroll
  for (int i = 0; i < 4; i++) {
    const int m = m0 + wm + i * 16 + lr;
    const int b_ = m >> 11, s_ = m & 2047;
#pragma unroll
    for (int j = 0; j < 4; j++) {
      const int n = n0 + wn + j * 16 + lg * 4;
      const int h_ = n >> 6, d_ = n & 63;
      half4 o;
#pragma unroll
      for (int r = 0; r < 4; r++) o[r] = (half_t)(acc[i][j][r] * esc);
      *reinterpret_cast<half4*>(
          &Cg[(((size_t)b_ * NH + h_) * SEQ + s_) * DHEAD + d_]) = o;
    }
  }
#undef STAGE_QKV
#undef COMP_QKV
}

// ---------------- O GEMM: BM=128, BN=64, BK=32, grid 512, 2D XCD chunking ------------
__global__ __launch_bounds__(256) void gemm_o(const half_t* __restrict__ Ag,
                                              const half_t* __restrict__ Bg,
                                              float* __restrict__ Cg) {
  __shared__ half_t As[2][128 * 32];
  __shared__ half_t Bs[2][64 * 32];
  const int tid = threadIdx.x, lane = tid & 63, w = tid >> 6;
  const int lr = lane & 15, lg = lane >> 4;
  const int flat = blockIdx.x;
  const int xcd = flat & 7, bi = flat >> 3;
  const int m0 = (xcd * 4 + (bi >> 4)) * 128;
  const int n0 = (bi & 15) * 64;
  const int wm = (w >> 1) * 64, wn = (w & 1) * 32;
  floatx4 acc[4][2] = {};

  const half_t* aSrc[2]; int dstOff[2];
#pragma unroll
  for (int j = 0; j < 2; j++) {
    int id = tid + j * 256;
    aSrc[j] = Ag + (size_t)(m0 + (id >> 2)) * DM + (id & 3) * 8;
    dstOff[j] = id * 8;
  }
  const half_t* bSrc = Bg + (size_t)(n0 + (tid >> 2)) * DM + (tid & 3) * 8;

#define STAGE_O(BUF, K0)                                                      \
  {                                                                           \
    _Pragma("unroll")                                                         \
    for (int j = 0; j < 2; j++)                                               \
      gload_lds16(aSrc[j] + (K0), &As[BUF][dstOff[j]]);                       \
    gload_lds16(bSrc + (K0), &Bs[BUF][tid * 8]);                              \
  }
#define COMP_O(BUF)                                                           \
  {                                                                           \
    half8 a[4], b[2];                                                         \
    _Pragma("unroll")                                                         \
    for (int i = 0; i < 4; i++)                                               \
      a[i] = *reinterpret_cast<half8*>(&As[BUF][(wm + i * 16 + lr) * 32 + lg * 8]); \
    _Pragma("unroll")                                                         \
    for (int j = 0; j < 2; j++)                                               \
      b[j] = *reinterpret_cast<half8*>(&Bs[BUF][(wn + j * 16 + lr) * 32 + lg * 8]); \
    _Pragma("unroll")                                                         \
    for (int i = 0; i < 4; i++)                                               \
      _Pragma("unroll")                                                       \
      for (int j = 0; j < 2; j++)                                             \
        acc[i][j] = __builtin_amdgcn_mfma_f32_16x16x32_f16(b[j], a[i], acc[i][j], 0, 0, 0); \
  }

  STAGE_O(0, 0);
  __syncthreads();
  int buf = 0;
#pragma unroll 1
  for (int t = 0; t < 31; t++) {
    STAGE_O(buf ^ 1, (t + 1) * 32);
    COMP_O(buf);
    __syncthreads();
    buf ^= 1;
  }
  COMP_O(buf);

#pragma unroll
  for (int i = 0; i < 4; i++) {
    const int m = m0 + wm + i * 16 + lr;
#pragma unroll
    for (int j = 0; j < 2; j++) {
      const int n = n0 + wn + j * 16 + lg * 4;
      floatx4 o = acc[i][j];
      *reinterpret_cast<floatx4*>(&Cg[(size_t)m * DM + n]) = o;
    }
  }
#undef STAGE_O
#undef COMP_O
}

// ---------------- causal flash attention v4.1: dbuf KV, 1 barrier/tile --------------
// Round-12 kernel with double-buffered Ks/Vt: iteration t reads buf, writes buf^1
// (disjoint); the single end-of-iter barrier publishes buf^1 AND orders this iter's
// reads-of-buf before next iter's writes-to-buf (round-5 proven pattern).
__global__ __launch_bounds__(512) void attn_fwd(const half_t* __restrict__ Q,
                                                const half_t* __restrict__ K,
                                                const half_t* __restrict__ V,
                                                half_t* __restrict__ P,
                                                float* __restrict__ L) {
  __shared__ half_t Ks[2][64][72];
  __shared__ half_t Vt[2][80][72];     // rows 0..63 V^T; 64 ones; 65..79 zero
  const int tid = threadIdx.x, lane = tid & 63, w = tid >> 6;
  const int lr = lane & 15, lg = lane >> 4;

  const int flat = blockIdx.x;               // 0..1023
  const int xcd = flat & 7, idx = flat >> 3; // 0..127
  const int qblk = 15 - (idx >> 3);          // heavy first, 128-row q-blocks
  const int sub = idx & 7;
  const int combo = xcd * 4 + (sub >> 1);
  const int split = sub & 1;
  const int h = combo & 15, b = combo >> 4;

  const size_t bh = ((size_t)b * NH + h) * SEQ * DHEAD;
  const int q0 = qblk * 128 + w * 16;        // wave's 16 q-rows
  const int nt = 2 * (qblk + 1);
  const int h0 = qblk + 1;
  const int t0 = split ? h0 : 0;
  const int t1 = split ? nt : h0;

  for (int i2 = tid; i2 < 16 * 72; i2 += 512) {
    int d = i2 / 72, kv = i2 % 72;
    half_t val = (d == 0) ? (half_t)1.0f : (half_t)0.0f;
    Vt[0][64 + d][kv] = val;
    Vt[1][64 + d][kv] = val;
  }

  half8 qf[2];
#pragma unroll
  for (int ks = 0; ks < 2; ks++)
    qf[ks] = *reinterpret_cast<const half8*>(
        Q + bh + (size_t)(q0 + lr) * DHEAD + ks * 32 + lg * 8);

  floatx4 accO[5] = {};   // j<4: O[d rows][q cols]; j=4: row-sum tile

  half8 kr, vr;
#define LOADT(t)                                                              \
  {                                                                           \
    const int kvb2 = (t) * KVB;                                               \
    kr = *reinterpret_cast<const half8*>(                                     \
        K + bh + (size_t)(kvb2 + (tid >> 3)) * DHEAD + (tid & 7) * 8);        \
    vr = *reinterpret_cast<const half8*>(                                     \
        V + bh + (size_t)(kvb2 + (tid & 63)) * DHEAD + (tid >> 6) * 8);       \
  }
#define WRITET(BUF)                                                           \
  {                                                                           \
    *reinterpret_cast<half8*>(&Ks[BUF][tid >> 3][(tid & 7) * 8]) = kr;        \
    int vrow = tid & 63, vcol = (tid >> 6) * 8;                               \
    _Pragma("unroll")                                                         \
    for (int e = 0; e < 8; e++) Vt[BUF][vcol + e][vrow] = vr[e];              \
  }

  LOADT(t0);
  WRITET(0);
  __syncthreads();
  int buf = 0;

#pragma unroll 1
  for (int t = t0; t < t1; t++) {
    const int kvbase = t * KVB;
    if (t + 1 < t1) LOADT(t + 1);            // issue early: hides under compute
    if (kvbase <= q0 + 15) {                 // wave has visible kv in this tile
      const bool need_mask = (kvbase + KVB - 1) > q0;
      // S^T = K Q^T : lane holds q=lr, kv = jt*16 + lg*4 + r
      floatx4 s[4];
#pragma unroll
      for (int jt = 0; jt < 4; jt++) {
        floatx4 a0 = {};
#pragma unroll
        for (int ks = 0; ks < 2; ks++) {
          half8 ak = *reinterpret_cast<half8*>(&Ks[buf][jt * 16 + lr][ks * 32 + lg * 8]);
          a0 = __builtin_amdgcn_mfma_f32_16x16x32_f16(ak, qf[ks], a0, 0, 0, 0);
        }
        s[jt] = a0;
      }
      const int qq = q0 + lr;
#pragma unroll
      for (int jt = 0; jt < 4; jt++)
#pragma unroll
        for (int r = 0; r < 4; r++) {
          float pp = fast_exp2(s[jt][r]);
          if (need_mask) {
            int kv = kvbase + jt * 16 + lg * 4 + r;
            if (kv > qq) pp = 0.f;
          }
          s[jt][r] = pp;
        }
      // P B-fragments straight from registers (k-slot perm):
      half8 pb[2];
#pragma unroll
      for (int ks = 0; ks < 2; ks++) {
#pragma unroll
        for (int e = 0; e < 4; e++) {
          pb[ks][e]     = (half_t)s[2 * ks][e];
          pb[ks][4 + e] = (half_t)s[2 * ks + 1][e];
        }
      }
      // PV: A = V^T fragments in the SAME permuted kv order (2x b64 each)
#pragma unroll
      for (int j = 0; j < 5; j++) {
#pragma unroll
        for (int ks = 0; ks < 2; ks++) {
          half4 x = *reinterpret_cast<half4*>(&Vt[buf][j * 16 + lr][ks * 32 + lg * 4]);
          half4 y = *reinterpret_cast<half4*>(&Vt[buf][j * 16 + lr][ks * 32 + 16 + lg * 4]);
          half8 av;
          av[0] = x[0]; av[1] = x[1]; av[2] = x[2]; av[3] = x[3];
          av[4] = y[0]; av[5] = y[1]; av[6] = y[2]; av[7] = y[3];
          accO[j] = __builtin_amdgcn_mfma_f32_16x16x32_f16(av, pb[ks], accO[j], 0, 0, 0);
        }
      }
    }
    if (t + 1 < t1) {
      WRITET(buf ^ 1);                       // disjoint buffer: no barrier needed first
      __syncthreads();                       // publish buf^1; order reads(buf) < writes(buf)
      buf ^= 1;
    }
  }

  // epilogue: lane holds q = q0+lr, d = j*16 + lg*4 + r -> half4 stores
  half_t* Pw = P + (size_t)split * EOFF;
  float*  Lw = L + (size_t)split * NROW;
  {
    const int q = q0 + lr;
    const size_t rowbase = bh + (size_t)q * DHEAD;
#pragma unroll
    for (int j = 0; j < 4; j++) {
      half4 o;
#pragma unroll
      for (int r = 0; r < 4; r++) o[r] = (half_t)accO[j][r];
      *reinterpret_cast<half4*>(&Pw[rowbase + j * 16 + lg * 4]) = o;
    }
    if (lg == 0)
      Lw[((size_t)b * NH + h) * SEQ + q] = accO[4][0];
  }
#undef LOADT
#undef WRITET
}

// ---------------- combine: O = (P0 + P1) / (l0 + l1), scatter heads -> [B][S][DM] ----
__global__ __launch_bounds__(256) void attn_combine(const half_t* __restrict__ P,
                                                    const float* __restrict__ L,
                                                    half_t* __restrict__ Ab) {
  size_t i = (size_t)blockIdx.x * 256 + threadIdx.x;   // chunk of 8, total E/8
  half8 p0 = *reinterpret_cast<const half8*>(P + i * 8);
  half8 p1 = *reinterpret_cast<const half8*>(P + EOFF + i * 8);
  size_t row = i >> 3;                 // [b][h][s]
  float l = L[row] + L[NROW + row];
  float inv = 1.0f / l;
  int s_ = (int)(row % SEQ);
  int h_ = (int)((row / SEQ) % NH);
  int b_ = (int)(row / ((size_t)SEQ * NH));
  int d0 = (int)(i & 7) * 8;
  half8 o;
#pragma unroll
  for (int e = 0; e < 8; e++)
    o[e] = (half_t)(((float)p0[e] + (float)p1[e]) * inv);
  *reinterpret_cast<half8*>(Ab + ((size_t)b_ * SEQ + s_) * DM + h_ * DHEAD + d0) = o;
}

extern "C" void kernel_launch(void* const* d_in, const int* in_sizes, int n_in,
                              void* d_out, int out_size, void* d_ws, size_t ws_size,
                              hipStream_t stream) {
  const float* q_in = (const float*)d_in[0];
  const float* k_in = (const float*)d_in[1];
  const float* v_in = (const float*)d_in[2];
  const float* Wq   = (const float*)d_in[5];
  const float* Wk   = (const float*)d_in[6];
  const float* Wv   = (const float*)d_in[7];
  const float* Wo   = (const float*)d_in[8];

  const size_t E = EOFF;
  const size_t W = (size_t)DM * DM;
  half_t* ws  = (half_t*)d_ws;
  half_t* Xq  = ws;             // cvt X_q; later: combine output Ab
  half_t* Xk  = ws + E;         // cvt X_k; later: attn partial P (2E)
  half_t* Xv  = ws + 2 * E;
  half_t* Wqh = ws + 3 * E;     // f16 Wq; later: attn partial L (2 x 256KB)
  half_t* Wkh = Wqh + W;
  half_t* Wvh = Wkh + W;
  half_t* Woh = Wvh + W;
  half_t* Qb  = ws + 4 * E;
  half_t* Kb  = ws + 5 * E;
  half_t* Vb  = ws + 6 * E;
  half_t* Ab  = Xq;
  half_t* Pp  = Xk;             // partial O, [2][B][H][S][64]
  float*  Lp  = (float*)Wqh;    // partial sums, [2][NROW]
  if (ws_size < 7 * E * sizeof(half_t)) return;

  cvt_all<<<dim3(2048, 7), 256, 0, stream>>>(q_in, k_in, v_in, Wq, Wk, Wv, Wo,
                                             Xq, Xk, Xv, Wqh, Wkh, Wvh, Woh);
  gemm_qkv<<<768, 256, 0, stream>>>(Xq, Xk, Xv, Wqh, Wkh, Wvh, Qb, Kb, Vb);
  attn_fwd<<<1024, 512, 0, stream>>>(Qb, Kb, Vb, Pp, Lp);
  attn_combine<<<2048, 256, 0, stream>>>(Pp, Lp, Ab);
  gemm_o<<<512, 256, 0, stream>>>(Ab, Woh, (float*)d_out);
}

// Round 18
// 122.593 us; speedup vs baseline: 1.1198x; 1.0471x over previous
//
#include <hip/hip_runtime.h>

#define DM   1024
#define SEQ  2048
#define BATCH 2
#define NH   16
#define DHEAD 64
#define MTOT (BATCH*SEQ)   // 4096
#define KVB  64
#define EOFF ((size_t)MTOT * DM)
#define NROW (BATCH * NH * SEQ)   // 65536 head-rows

typedef _Float16 half_t;
typedef _Float16 half4 __attribute__((ext_vector_type(4)));
typedef _Float16 half8 __attribute__((ext_vector_type(8)));
typedef float    floatx4 __attribute__((ext_vector_type(4)));

#define SCALE2 0.18033688f   // (1/8) * log2(e)

__device__ __forceinline__ float fast_exp2(float x) {
  float r;
  asm volatile("v_exp_f32 %0, %1" : "=v"(r) : "v"(x));
  return r;
}

__device__ __forceinline__ void gload_lds16(const half_t* g, half_t* l) {
  __builtin_amdgcn_global_load_lds(
      (const __attribute__((address_space(1))) void*)g,
      (__attribute__((address_space(3))) void*)l, 16, 0, 0);
}

// ---------------- fused f32 -> f16 convert (all 7 arrays, one launch) ----------------
__global__ __launch_bounds__(256) void cvt_all(const float* __restrict__ q, const float* __restrict__ k,
                                               const float* __restrict__ v, const float* __restrict__ wq,
                                               const float* __restrict__ wk, const float* __restrict__ wv,
                                               const float* __restrict__ wo,
                                               half_t* __restrict__ dq, half_t* __restrict__ dk,
                                               half_t* __restrict__ dv, half_t* __restrict__ dwq,
                                               half_t* __restrict__ dwk, half_t* __restrict__ dwv,
                                               half_t* __restrict__ dwo) {
  const int y = blockIdx.y;
  const float* s; half_t* d; int n8;
  const int En8 = MTOT * DM / 8, Wn8 = DM * DM / 8;
  switch (y) {
    case 0: s = q;  d = dq;  n8 = En8; break;
    case 1: s = k;  d = dk;  n8 = En8; break;
    case 2: s = v;  d = dv;  n8 = En8; break;
    case 3: s = wq; d = dwq; n8 = Wn8; break;
    case 4: s = wk; d = dwk; n8 = Wn8; break;
    case 5: s = wv; d = dwv; n8 = Wn8; break;
    default: s = wo; d = dwo; n8 = Wn8; break;
  }
  int i = blockIdx.x * 256 + threadIdx.x;
  if (i >= n8) return;
  const float4* sp = reinterpret_cast<const float4*>(s);
  float4 u = sp[(size_t)i * 2], w = sp[(size_t)i * 2 + 1];
  half8 h;
  h[0] = (half_t)u.x; h[1] = (half_t)u.y; h[2] = (half_t)u.z; h[3] = (half_t)u.w;
  h[4] = (half_t)w.x; h[5] = (half_t)w.y; h[6] = (half_t)w.z; h[7] = (half_t)w.w;
  *reinterpret_cast<half8*>(d + (size_t)i * 8) = h;
}

// ---------------- QKV GEMM: m97 structure, 2D XCD chunking, swapped epilogue ---------
// grid 768 = 3 x 256. Per XCD: 4 m-tiles x 8 n-tiles (A 1MB + B 2MB L2-resident).
__global__ __launch_bounds__(256) void gemm_qkv(const half_t* __restrict__ Xq,
                                                const half_t* __restrict__ Xk,
                                                const half_t* __restrict__ Xv,
                                                const half_t* __restrict__ Wq,
                                                const half_t* __restrict__ Wk,
                                                const half_t* __restrict__ Wv,
                                                half_t* __restrict__ Qb,
                                                half_t* __restrict__ Kb,
                                                half_t* __restrict__ Vb) {
  __shared__ half_t As[2][128 * 32];
  __shared__ half_t Bs[2][128 * 32];
  const int which = blockIdx.x >> 8;
  const int flat = blockIdx.x & 255;
  const half_t* Ag = (which == 0) ? Xq : (which == 1) ? Xk : Xv;
  const half_t* Bg = (which == 0) ? Wq : (which == 1) ? Wk : Wv;
  half_t* Cg       = (which == 0) ? Qb : (which == 1) ? Kb : Vb;
  const float esc  = (which == 0) ? SCALE2 : 1.0f;

  const int tid = threadIdx.x, lane = tid & 63, w = tid >> 6;
  const int lr = lane & 15, lg = lane >> 4;
  const int xcd = flat & 7, bi = flat >> 3;
  const int m0 = (xcd * 4 + (bi >> 3)) * 128;
  const int n0 = (bi & 7) * 128;
  const int wm = (w >> 1) * 64, wn = (w & 1) * 64;
  floatx4 acc[4][4] = {};

  const half_t* aSrc[2]; const half_t* bSrc[2]; int dstOff[2];
#pragma unroll
  for (int j = 0; j < 2; j++) {
    int id = tid + j * 256;
    aSrc[j] = Ag + (size_t)(m0 + (id >> 2)) * DM + (id & 3) * 8;
    bSrc[j] = Bg + (size_t)(n0 + (id >> 2)) * DM + (id & 3) * 8;
    dstOff[j] = id * 8;
  }

#define STAGE_QKV(BUF, K0)                                                    \
  {                                                                           \
    _Pragma("unroll")                                                         \
    for (int j = 0; j < 2; j++) {                                             \
      gload_lds16(aSrc[j] + (K0), &As[BUF][dstOff[j]]);                       \
      gload_lds16(bSrc[j] + (K0), &Bs[BUF][dstOff[j]]);                       \
    }                                                                         \
  }
#define COMP_QKV(BUF)                                                         \
  {                                                                           \
    half8 a[4], b[4];                                                         \
    _Pragma("unroll")                                                         \
    for (int i = 0; i < 4; i++)                                               \
      a[i] = *reinterpret_cast<half8*>(&As[BUF][(wm + i * 16 + lr) * 32 + lg * 8]); \
    _Pragma("unroll")                                                         \
    for (int j = 0; j < 4; j++)                                               \
      b[j] = *reinterpret_cast<half8*>(&Bs[BUF][(wn + j * 16 + lr) * 32 + lg * 8]); \
    _Pragma("unroll")                                                         \
    for (int i = 0; i < 4; i++)                                               \
      _Pragma("unroll")                                                       \
      for (int j = 0; j < 4; j++)                                             \
        acc[i][j] = __builtin_amdgcn_mfma_f32_16x16x32_f16(b[j], a[i], acc[i][j], 0, 0, 0); \
  }

  STAGE_QKV(0, 0);
  __syncthreads();
  int buf = 0;
#pragma unroll 1
  for (int t = 0; t < 31; t++) {
    STAGE_QKV(buf ^ 1, (t + 1) * 32);
    COMP_QKV(buf);
    __syncthreads();
    buf ^= 1;
  }
  COMP_QKV(buf);

  // epilogue: lane holds 4 consecutive n (row axis), fixed m (col = lr)
#pragma unroll
  for (int i = 0; i < 4; i++) {
    const int m = m0 + wm + i * 16 + lr;
    const int b_ = m >> 11, s_ = m & 2047;
#pragma unroll
    for (int j = 0; j < 4; j++) {
      const int n = n0 + wn + j * 16 + lg * 4;
      const int h_ = n >> 6, d_ = n & 63;
      half4 o;
#pragma unroll
      for (int r = 0; r < 4; r++) o[r] = (half_t)(acc[i][j][r] * esc);
      *reinterpret_cast<half4*>(
          &Cg[(((size_t)b_ * NH + h_) * SEQ + s_) * DHEAD + d_]) = o;
    }
  }
#undef STAGE_QKV
#undef COMP_QKV
}

// ---------------- O GEMM: BM=128, BN=64, BK=32, grid 512, 2D XCD chunking ------------
__global__ __launch_bounds__(256) void gemm_o(const half_t* __restrict__ Ag,
                                              const half_t* __restrict__ Bg,
                                              float* __restrict__ Cg) {
  __shared__ half_t As[2][128 * 32];
  __shared__ half_t Bs[2][64 * 32];
  const int tid = threadIdx.x, lane = tid & 63, w = tid >> 6;
  const int lr = lane & 15, lg = lane >> 4;
  const int flat = blockIdx.x;
  const int xcd = flat & 7, bi = flat >> 3;
  const int m0 = (xcd * 4 + (bi >> 4)) * 128;
  const int n0 = (bi & 15) * 64;
  const int wm = (w >> 1) * 64, wn = (w & 1) * 32;
  floatx4 acc[4][2] = {};

  const half_t* aSrc[2]; int dstOff[2];
#pragma unroll
  for (int j = 0; j < 2; j++) {
    int id = tid + j * 256;
    aSrc[j] = Ag + (size_t)(m0 + (id >> 2)) * DM + (id & 3) * 8;
    dstOff[j] = id * 8;
  }
  const half_t* bSrc = Bg + (size_t)(n0 + (tid >> 2)) * DM + (tid & 3) * 8;

#define STAGE_O(BUF, K0)                                                      \
  {                                                                           \
    _Pragma("unroll")                                                         \
    for (int j = 0; j < 2; j++)                                               \
      gload_lds16(aSrc[j] + (K0), &As[BUF][dstOff[j]]);                       \
    gload_lds16(bSrc + (K0), &Bs[BUF][tid * 8]);                              \
  }
#define COMP_O(BUF)                                                           \
  {                                                                           \
    half8 a[4], b[2];                                                         \
    _Pragma("unroll")                                                         \
    for (int i = 0; i < 4; i++)                                               \
      a[i] = *reinterpret_cast<half8*>(&As[BUF][(wm + i * 16 + lr) * 32 + lg * 8]); \
    _Pragma("unroll")                                                         \
    for (int j = 0; j < 2; j++)                                               \
      b[j] = *reinterpret_cast<half8*>(&Bs[BUF][(wn + j * 16 + lr) * 32 + lg * 8]); \
    _Pragma("unroll")                                                         \
    for (int i = 0; i < 4; i++)                                               \
      _Pragma("unroll")                                                       \
      for (int j = 0; j < 2; j++)                                             \
        acc[i][j] = __builtin_amdgcn_mfma_f32_16x16x32_f16(b[j], a[i], acc[i][j], 0, 0, 0); \
  }

  STAGE_O(0, 0);
  __syncthreads();
  int buf = 0;
#pragma unroll 1
  for (int t = 0; t < 31; t++) {
    STAGE_O(buf ^ 1, (t + 1) * 32);
    COMP_O(buf);
    __syncthreads();
    buf ^= 1;
  }
  COMP_O(buf);

#pragma unroll
  for (int i = 0; i < 4; i++) {
    const int m = m0 + wm + i * 16 + lr;
#pragma unroll
    for (int j = 0; j < 2; j++) {
      const int n = n0 + wn + j * 16 + lg * 4;
      floatx4 o = acc[i][j];
      *reinterpret_cast<floatx4*>(&Cg[(size_t)m * DM + n]) = o;
    }
  }
#undef STAGE_O
#undef COMP_O
}

// ---------------- causal flash attention v4.2: dbuf KV + permuted Vt ----------------
// Vt kv-axis stored pre-permuted with C(kv) = (kv>>5)*32 + ((kv>>2)&3)*8
// + ((kv>>4)&1)*4 + (kv&3), so each lane's PV A-fragment (the k-slot-permuted
// order matching pb) is ONE contiguous 16B ds_read_b128 — replaces 2x b64 + movs.
__global__ __launch_bounds__(512) void attn_fwd(const half_t* __restrict__ Q,
                                                const half_t* __restrict__ K,
                                                const half_t* __restrict__ V,
                                                half_t* __restrict__ P,
                                                float* __restrict__ L) {
  __shared__ half_t Ks[2][64][72];
  __shared__ half_t Vt[2][80][72];     // rows 0..63 V^T (perm cols); 64 ones; 65..79 zero
  const int tid = threadIdx.x, lane = tid & 63, w = tid >> 6;
  const int lr = lane & 15, lg = lane >> 4;

  const int flat = blockIdx.x;               // 0..1023
  const int xcd = flat & 7, idx = flat >> 3; // 0..127
  const int qblk = 15 - (idx >> 3);          // heavy first, 128-row q-blocks
  const int sub = idx & 7;
  const int combo = xcd * 4 + (sub >> 1);
  const int split = sub & 1;
  const int h = combo & 15, b = combo >> 4;

  const size_t bh = ((size_t)b * NH + h) * SEQ * DHEAD;
  const int q0 = qblk * 128 + w * 16;        // wave's 16 q-rows
  const int nt = 2 * (qblk + 1);
  const int h0 = qblk + 1;
  const int t0 = split ? h0 : 0;
  const int t1 = split ? nt : h0;

  for (int i2 = tid; i2 < 16 * 72; i2 += 512) {
    int d = i2 / 72, kv = i2 % 72;
    half_t val = (d == 0) ? (half_t)1.0f : (half_t)0.0f;
    Vt[0][64 + d][kv] = val;
    Vt[1][64 + d][kv] = val;
  }

  half8 qf[2];
#pragma unroll
  for (int ks = 0; ks < 2; ks++)
    qf[ks] = *reinterpret_cast<const half8*>(
        Q + bh + (size_t)(q0 + lr) * DHEAD + ks * 32 + lg * 8);

  floatx4 accO[5] = {};   // j<4: O[d rows][q cols]; j=4: row-sum tile

  half8 kr, vr;
#define LOADT(t)                                                              \
  {                                                                           \
    const int kvb2 = (t) * KVB;                                               \
    kr = *reinterpret_cast<const half8*>(                                     \
        K + bh + (size_t)(kvb2 + (tid >> 3)) * DHEAD + (tid & 7) * 8);        \
    vr = *reinterpret_cast<const half8*>(                                     \
        V + bh + (size_t)(kvb2 + (tid & 63)) * DHEAD + (tid >> 6) * 8);       \
  }
// permuted kv column: C(kv) = (kv>>5)*32 + ((kv>>2)&3)*8 + ((kv>>4)&1)*4 + (kv&3)
#define WRITET(BUF)                                                           \
  {                                                                           \
    *reinterpret_cast<half8*>(&Ks[BUF][tid >> 3][(tid & 7) * 8]) = kr;        \
    int vrow = tid & 63, vcol = (tid >> 6) * 8;                               \
    int vp = ((vrow >> 5) << 5) + (((vrow >> 2) & 3) << 3)                    \
           + (((vrow >> 4) & 1) << 2) + (vrow & 3);                           \
    _Pragma("unroll")                                                         \
    for (int e = 0; e < 8; e++) Vt[BUF][vcol + e][vp] = vr[e];                \
  }

  LOADT(t0);
  WRITET(0);
  __syncthreads();
  int buf = 0;

#pragma unroll 1
  for (int t = t0; t < t1; t++) {
    const int kvbase = t * KVB;
    if (t + 1 < t1) LOADT(t + 1);            // issue early: hides under compute
    if (kvbase <= q0 + 15) {                 // wave has visible kv in this tile
      const bool need_mask = (kvbase + KVB - 1) > q0;
      // S^T = K Q^T : lane holds q=lr, kv = jt*16 + lg*4 + r
      floatx4 s[4];
#pragma unroll
      for (int jt = 0; jt < 4; jt++) {
        floatx4 a0 = {};
#pragma unroll
        for (int ks = 0; ks < 2; ks++) {
          half8 ak = *reinterpret_cast<half8*>(&Ks[buf][jt * 16 + lr][ks * 32 + lg * 8]);
          a0 = __builtin_amdgcn_mfma_f32_16x16x32_f16(ak, qf[ks], a0, 0, 0, 0);
        }
        s[jt] = a0;
      }
      const int qq = q0 + lr;
#pragma unroll
      for (int jt = 0; jt < 4; jt++)
#pragma unroll
        for (int r = 0; r < 4; r++) {
          float pp = fast_exp2(s[jt][r]);
          if (need_mask) {
            int kv = kvbase + jt * 16 + lg * 4 + r;
            if (kv > qq) pp = 0.f;
          }
          s[jt][r] = pp;
        }
      // P B-fragments straight from registers (k-slot perm):
      half8 pb[2];
#pragma unroll
      for (int ks = 0; ks < 2; ks++) {
#pragma unroll
        for (int e = 0; e < 4; e++) {
          pb[ks][e]     = (half_t)s[2 * ks][e];
          pb[ks][4 + e] = (half_t)s[2 * ks + 1][e];
        }
      }
      // PV: A = V^T fragment, contiguous b128 in the permuted layout
#pragma unroll
      for (int j = 0; j < 5; j++) {
#pragma unroll
        for (int ks = 0; ks < 2; ks++) {
          half8 av = *reinterpret_cast<half8*>(&Vt[buf][j * 16 + lr][ks * 32 + lg * 8]);
          accO[j] = __builtin_amdgcn_mfma_f32_16x16x32_f16(av, pb[ks], accO[j], 0, 0, 0);
        }
      }
    }
    if (t + 1 < t1) {
      WRITET(buf ^ 1);                       // disjoint buffer: no barrier needed first
      __syncthreads();                       // publish buf^1; order reads(buf) < writes(buf)
      buf ^= 1;
    }
  }

  // epilogue: lane holds q = q0+lr, d = j*16 + lg*4 + r -> half4 stores
  half_t* Pw = P + (size_t)split * EOFF;
  float*  Lw = L + (size_t)split * NROW;
  {
    const int q = q0 + lr;
    const size_t rowbase = bh + (size_t)q * DHEAD;
#pragma unroll
    for (int j = 0; j < 4; j++) {
      half4 o;
#pragma unroll
      for (int r = 0; r < 4; r++) o[r] = (half_t)accO[j][r];
      *reinterpret_cast<half4*>(&Pw[rowbase + j * 16 + lg * 4]) = o;
    }
    if (lg == 0)
      Lw[((size_t)b * NH + h) * SEQ + q] = accO[4][0];
  }
#undef LOADT
#undef WRITET
}

// ---------------- combine: O = (P0 + P1) / (l0 + l1), scatter heads -> [B][S][DM] ----
__global__ __launch_bounds__(256) void attn_combine(const half_t* __restrict__ P,
                                                    const float* __restrict__ L,
                                                    half_t* __restrict__ Ab) {
  size_t i = (size_t)blockIdx.x * 256 + threadIdx.x;   // chunk of 8, total E/8
  half8 p0 = *reinterpret_cast<const half8*>(P + i * 8);
  half8 p1 = *reinterpret_cast<const half8*>(P + EOFF + i * 8);
  size_t row = i >> 3;                 // [b][h][s]
  float l = L[row] + L[NROW + row];
  float inv = 1.0f / l;
  int s_ = (int)(row % SEQ);
  int h_ = (int)((row / SEQ) % NH);
  int b_ = (int)(row / ((size_t)SEQ * NH));
  int d0 = (int)(i & 7) * 8;
  half8 o;
#pragma unroll
  for (int e = 0; e < 8; e++)
    o[e] = (half_t)(((float)p0[e] + (float)p1[e]) * inv);
  *reinterpret_cast<half8*>(Ab + ((size_t)b_ * SEQ + s_) * DM + h_ * DHEAD + d0) = o;
}

extern "C" void kernel_launch(void* const* d_in, const int* in_sizes, int n_in,
                              void* d_out, int out_size, void* d_ws, size_t ws_size,
                              hipStream_t stream) {
  const float* q_in = (const float*)d_in[0];
  const float* k_in = (const float*)d_in[1];
  const float* v_in = (const float*)d_in[2];
  const float* Wq   = (const float*)d_in[5];
  const float* Wk   = (const float*)d_in[6];
  const float* Wv   = (const float*)d_in[7];
  const float* Wo   = (const float*)d_in[8];

  const size_t E = EOFF;
  const size_t W = (size_t)DM * DM;
  half_t* ws  = (half_t*)d_ws;
  half_t* Xq  = ws;             // cvt X_q; later: combine output Ab
  half_t* Xk  = ws + E;         // cvt X_k; later: attn partial P (2E)
  half_t* Xv  = ws + 2 * E;
  half_t* Wqh = ws + 3 * E;     // f16 Wq; later: attn partial L (2 x 256KB)
  half_t* Wkh = Wqh + W;
  half_t* Wvh = Wkh + W;
  half_t* Woh = Wvh + W;
  half_t* Qb  = ws + 4 * E;
  half_t* Kb  = ws + 5 * E;
  half_t* Vb  = ws + 6 * E;
  half_t* Ab  = Xq;
  half_t* Pp  = Xk;             // partial O, [2][B][H][S][64]
  float*  Lp  = (float*)Wqh;    // partial sums, [2][NROW]
  if (ws_size < 7 * E * sizeof(half_t)) return;

  cvt_all<<<dim3(2048, 7), 256, 0, stream>>>(q_in, k_in, v_in, Wq, Wk, Wv, Wo,
                                             Xq, Xk, Xv, Wqh, Wkh, Wvh, Woh);
  gemm_qkv<<<768, 256, 0, stream>>>(Xq, Xk, Xv, Wqh, Wkh, Wvh, Qb, Kb, Vb);
  attn_fwd<<<1024, 512, 0, stream>>>(Qb, Kb, Vb, Pp, Lp);
  attn_combine<<<2048, 256, 0, stream>>>(Pp, Lp, Ab);
  gemm_o<<<512, 256, 0, stream>>>(Ab, Woh, (float*)d_out);
}

// Round 20
// 122.259 us; speedup vs baseline: 1.1229x; 1.0027x over previous
//
#include <hip/hip_runtime.h>

#define DM   1024
#define SEQ  2048
#define BATCH 2
#define NH   16
#define DHEAD 64
#define MTOT (BATCH*SEQ)   // 4096
#define KVB  64
#define EOFF ((size_t)MTOT * DM)
#define NROW (BATCH * NH * SEQ)   // 65536 head-rows

typedef _Float16 half_t;
typedef _Float16 half4 __attribute__((ext_vector_type(4)));
typedef _Float16 half8 __attribute__((ext_vector_type(8)));
typedef float    floatx4 __attribute__((ext_vector_type(4)));

#define SCALE2 0.18033688f   // (1/8) * log2(e)

__device__ __forceinline__ float fast_exp2(float x) {
  float r;
  asm volatile("v_exp_f32 %0, %1" : "=v"(r) : "v"(x));
  return r;
}

__device__ __forceinline__ void gload_lds16(const half_t* g, half_t* l) {
  __builtin_amdgcn_global_load_lds(
      (const __attribute__((address_space(1))) void*)g,
      (__attribute__((address_space(3))) void*)l, 16, 0, 0);
}

// ---------------- fused f32 -> f16 convert (all 7 arrays, one launch) ----------------
__global__ __launch_bounds__(256) void cvt_all(const float* __restrict__ q, const float* __restrict__ k,
                                               const float* __restrict__ v, const float* __restrict__ wq,
                                               const float* __restrict__ wk, const float* __restrict__ wv,
                                               const float* __restrict__ wo,
                                               half_t* __restrict__ dq, half_t* __restrict__ dk,
                                               half_t* __restrict__ dv, half_t* __restrict__ dwq,
                                               half_t* __restrict__ dwk, half_t* __restrict__ dwv,
                                               half_t* __restrict__ dwo) {
  const int y = blockIdx.y;
  const float* s; half_t* d; int n8;
  const int En8 = MTOT * DM / 8, Wn8 = DM * DM / 8;
  switch (y) {
    case 0: s = q;  d = dq;  n8 = En8; break;
    case 1: s = k;  d = dk;  n8 = En8; break;
    case 2: s = v;  d = dv;  n8 = En8; break;
    case 3: s = wq; d = dwq; n8 = Wn8; break;
    case 4: s = wk; d = dwk; n8 = Wn8; break;
    case 5: s = wv; d = dwv; n8 = Wn8; break;
    default: s = wo; d = dwo; n8 = Wn8; break;
  }
  int i = blockIdx.x * 256 + threadIdx.x;
  if (i >= n8) return;
  const float4* sp = reinterpret_cast<const float4*>(s);
  float4 u = sp[(size_t)i * 2], w = sp[(size_t)i * 2 + 1];
  half8 h;
  h[0] = (half_t)u.x; h[1] = (half_t)u.y; h[2] = (half_t)u.z; h[3] = (half_t)u.w;
  h[4] = (half_t)w.x; h[5] = (half_t)w.y; h[6] = (half_t)w.z; h[7] = (half_t)w.w;
  *reinterpret_cast<half8*>(d + (size_t)i * 8) = h;
}

// ---------------- QKV GEMM: m97 structure, 2D XCD chunking, swapped epilogue ---------
// grid 768 = 3 x 256. Per XCD: 4 m-tiles x 8 n-tiles (A 1MB + B 2MB L2-resident).
__global__ __launch_bounds__(256) void gemm_qkv(const half_t* __restrict__ Xq,
                                                const half_t* __restrict__ Xk,
                                                const half_t* __restrict__ Xv,
                                                const half_t* __restrict__ Wq,
                                                const half_t* __restrict__ Wk,
                                                const half_t* __restrict__ Wv,
                                                half_t* __restrict__ Qb,
                                                half_t* __restrict__ Kb,
                                                half_t* __restrict__ Vb) {
  __shared__ half_t As[2][128 * 32];
  __shared__ half_t Bs[2][128 * 32];
  const int which = blockIdx.x >> 8;
  const int flat = blockIdx.x & 255;
  const half_t* Ag = (which == 0) ? Xq : (which == 1) ? Xk : Xv;
  const half_t* Bg = (which == 0) ? Wq : (which == 1) ? Wk : Wv;
  half_t* Cg       = (which == 0) ? Qb : (which == 1) ? Kb : Vb;
  const float esc  = (which == 0) ? SCALE2 : 1.0f;

  const int tid = threadIdx.x, lane = tid & 63, w = tid >> 6;
  const int lr = lane & 15, lg = lane >> 4;
  const int xcd = flat & 7, bi = flat >> 3;
  const int m0 = (xcd * 4 + (bi >> 3)) * 128;
  const int n0 = (bi & 7) * 128;
  const int wm = (w >> 1) * 64, wn = (w & 1) * 64;
  floatx4 acc[4][4] = {};

  const half_t* aSrc[2]; const half_t* bSrc[2]; int dstOff[2];
#pragma unroll
  for (int j = 0; j < 2; j++) {
    int id = tid + j * 256;
    aSrc[j] = Ag + (size_t)(m0 + (id >> 2)) * DM + (id & 3) * 8;
    bSrc[j] = Bg + (size_t)(n0 + (id >> 2)) * DM + (id & 3) * 8;
    dstOff[j] = id * 8;
  }

#define STAGE_QKV(BUF, K0)                                                    \
  {                                                                           \
    _Pragma("unroll")                                                         \
    for (int j = 0; j < 2; j++) {                                             \
      gload_lds16(aSrc[j] + (K0), &As[BUF][dstOff[j]]);                       \
      gload_lds16(bSrc[j] + (K0), &Bs[BUF][dstOff[j]]);                       \
    }                                                                         \
  }
#define COMP_QKV(BUF)                                                         \
  {                                                                           \
    half8 a[4], b[4];                                                         \
    _Pragma("unroll")                                                         \
    for (int i = 0; i < 4; i++)                                               \
      a[i] = *reinterpret_cast<half8*>(&As[BUF][(wm + i * 16 + lr) * 32 + lg * 8]); \
    _Pragma("unroll")                                                         \
    for (int j = 0; j < 4; j++)                                               \
      b[j] = *reinterpret_cast<half8*>(&Bs[BUF][(wn + j * 16 + lr) * 32 + lg * 8]); \
    _Pragma("unroll")                                                         \
    for (int i = 0; i < 4; i++)                                               \
      _Pragma("unroll")                                                       \
      for (int j = 0; j < 4; j++)                                             \
        acc[i][j] = __builtin_amdgcn_mfma_f32_16x16x32_f16(b[j], a[i], acc[i][j], 0, 0, 0); \
  }

  STAGE_QKV(0, 0);
  __syncthreads();
  int buf = 0;
#pragma unroll 1
  for (int t = 0; t < 31; t++) {
    STAGE_QKV(buf ^ 1, (t + 1) * 32);
    COMP_QKV(buf);
    __syncthreads();
    buf ^= 1;
  }
  COMP_QKV(buf);

  // epilogue: lane holds 4 consecutive n (row axis), fixed m (col = lr)
#pragma unroll
  for (int i = 0; i < 4; i++) {
    const int m = m0 + wm + i * 16 + lr;
    const int b_ = m >> 11, s_ = m & 2047;
#pragma unroll
    for (int j = 0; j < 4; j++) {
      const int n = n0 + wn + j * 16 + lg * 4;
      const int h_ = n >> 6, d_ = n & 63;
      half4 o;
#pragma unroll
      for (int r = 0; r < 4; r++) o[r] = (half_t)(acc[i][j][r] * esc);
      *reinterpret_cast<half4*>(
          &Cg[(((size_t)b_ * NH + h_) * SEQ + s_) * DHEAD + d_]) = o;
    }
  }
#undef STAGE_QKV
#undef COMP_QKV
}

// ---------------- O GEMM: BM=128, BN=64, BK=32, grid 512, 2D XCD chunking ------------
__global__ __launch_bounds__(256) void gemm_o(const half_t* __restrict__ Ag,
                                              const half_t* __restrict__ Bg,
                                              float* __restrict__ Cg) {
  __shared__ half_t As[2][128 * 32];
  __shared__ half_t Bs[2][64 * 32];
  const int tid = threadIdx.x, lane = tid & 63, w = tid >> 6;
  const int lr = lane & 15, lg = lane >> 4;
  const int flat = blockIdx.x;
  const int xcd = flat & 7, bi = flat >> 3;
  const int m0 = (xcd * 4 + (bi >> 4)) * 128;
  const int n0 = (bi & 15) * 64;
  const int wm = (w >> 1) * 64, wn = (w & 1) * 32;
  floatx4 acc[4][2] = {};

  const half_t* aSrc[2]; int dstOff[2];
#pragma unroll
  for (int j = 0; j < 2; j++) {
    int id = tid + j * 256;
    aSrc[j] = Ag + (size_t)(m0 + (id >> 2)) * DM + (id & 3) * 8;
    dstOff[j] = id * 8;
  }
  const half_t* bSrc = Bg + (size_t)(n0 + (tid >> 2)) * DM + (tid & 3) * 8;

#define STAGE_O(BUF, K0)                                                      \
  {                                                                           \
    _Pragma("unroll")                                                         \
    for (int j = 0; j < 2; j++)                                               \
      gload_lds16(aSrc[j] + (K0), &As[BUF][dstOff[j]]);                       \
    gload_lds16(bSrc + (K0), &Bs[BUF][tid * 8]);                              \
  }
#define COMP_O(BUF)                                                           \
  {                                                                           \
    half8 a[4], b[2];                                                         \
    _Pragma("unroll")                                                         \
    for (int i = 0; i < 4; i++)                                               \
      a[i] = *reinterpret_cast<half8*>(&As[BUF][(wm + i * 16 + lr) * 32 + lg * 8]); \
    _Pragma("unroll")                                                         \
    for (int j = 0; j < 2; j++)                                               \
      b[j] = *reinterpret_cast<half8*>(&Bs[BUF][(wn + j * 16 + lr) * 32 + lg * 8]); \
    _Pragma("unroll")                                                         \
    for (int i = 0; i < 4; i++)                                               \
      _Pragma("unroll")                                                       \
      for (int j = 0; j < 2; j++)                                             \
        acc[i][j] = __builtin_amdgcn_mfma_f32_16x16x32_f16(b[j], a[i], acc[i][j], 0, 0, 0); \
  }

  STAGE_O(0, 0);
  __syncthreads();
  int buf = 0;
#pragma unroll 1
  for (int t = 0; t < 31; t++) {
    STAGE_O(buf ^ 1, (t + 1) * 32);
    COMP_O(buf);
    __syncthreads();
    buf ^= 1;
  }
  COMP_O(buf);

#pragma unroll
  for (int i = 0; i < 4; i++) {
    const int m = m0 + wm + i * 16 + lr;
#pragma unroll
    for (int j = 0; j < 2; j++) {
      const int n = n0 + wn + j * 16 + lg * 4;
      floatx4 o = acc[i][j];
      *reinterpret_cast<floatx4*>(&Cg[(size_t)m * DM + n]) = o;
    }
  }
#undef STAGE_O
#undef COMP_O
}

// ---------------- causal flash attention v4.2: dbuf KV + permuted Vt ----------------
// Vt kv-axis stored pre-permuted with C(kv) = (kv>>5)*32 + ((kv>>2)&3)*8
// + ((kv>>4)&1)*4 + (kv&3), so each lane's PV A-fragment (the k-slot-permuted
// order matching pb) is ONE contiguous 16B ds_read_b128.
__global__ __launch_bounds__(512) void attn_fwd(const half_t* __restrict__ Q,
                                                const half_t* __restrict__ K,
                                                const half_t* __restrict__ V,
                                                half_t* __restrict__ P,
                                                float* __restrict__ L) {
  __shared__ half_t Ks[2][64][72];
  __shared__ half_t Vt[2][80][72];     // rows 0..63 V^T (perm cols); 64 ones; 65..79 zero
  const int tid = threadIdx.x, lane = tid & 63, w = tid >> 6;
  const int lr = lane & 15, lg = lane >> 4;

  const int flat = blockIdx.x;               // 0..1023
  const int xcd = flat & 7, idx = flat >> 3; // 0..127
  const int qblk = 15 - (idx >> 3);          // heavy first, 128-row q-blocks
  const int sub = idx & 7;
  const int combo = xcd * 4 + (sub >> 1);
  const int split = sub & 1;
  const int h = combo & 15, b = combo >> 4;

  const size_t bh = ((size_t)b * NH + h) * SEQ * DHEAD;
  const int q0 = qblk * 128 + w * 16;        // wave's 16 q-rows
  const int nt = 2 * (qblk + 1);
  const int h0 = qblk + 1;
  const int t0 = split ? h0 : 0;
  const int t1 = split ? nt : h0;

  for (int i2 = tid; i2 < 16 * 72; i2 += 512) {
    int d = i2 / 72, kv = i2 % 72;
    half_t val = (d == 0) ? (half_t)1.0f : (half_t)0.0f;
    Vt[0][64 + d][kv] = val;
    Vt[1][64 + d][kv] = val;
  }

  half8 qf[2];
#pragma unroll
  for (int ks = 0; ks < 2; ks++)
    qf[ks] = *reinterpret_cast<const half8*>(
        Q + bh + (size_t)(q0 + lr) * DHEAD + ks * 32 + lg * 8);

  floatx4 accO[5] = {};   // j<4: O[d rows][q cols]; j=4: row-sum tile

  half8 kr, vr;
#define LOADT(t)                                                              \
  {                                                                           \
    const int kvb2 = (t) * KVB;                                               \
    kr = *reinterpret_cast<const half8*>(                                     \
        K + bh + (size_t)(kvb2 + (tid >> 3)) * DHEAD + (tid & 7) * 8);        \
    vr = *reinterpret_cast<const half8*>(                                     \
        V + bh + (size_t)(kvb2 + (tid & 63)) * DHEAD + (tid >> 6) * 8);       \
  }
// permuted kv column: C(kv) = (kv>>5)*32 + ((kv>>2)&3)*8 + ((kv>>4)&1)*4 + (kv&3)
#define WRITET(BUF)                                                           \
  {                                                                           \
    *reinterpret_cast<half8*>(&Ks[BUF][tid >> 3][(tid & 7) * 8]) = kr;        \
    int vrow = tid & 63, vcol = (tid >> 6) * 8;                               \
    int vp = ((vrow >> 5) << 5) + (((vrow >> 2) & 3) << 3)                    \
           + (((vrow >> 4) & 1) << 2) + (vrow & 3);                           \
    _Pragma("unroll")                                                         \
    for (int e = 0; e < 8; e++) Vt[BUF][vcol + e][vp] = vr[e];                \
  }

  LOADT(t0);
  WRITET(0);
  __syncthreads();
  int buf = 0;

#pragma unroll 1
  for (int t = t0; t < t1; t++) {
    const int kvbase = t * KVB;
    if (t + 1 < t1) LOADT(t + 1);            // issue early: hides under compute
    if (kvbase <= q0 + 15) {                 // wave has visible kv in this tile
      const bool need_mask = (kvbase + KVB - 1) > q0;
      // S^T = K Q^T : lane holds q=lr, kv = jt*16 + lg*4 + r
      floatx4 s[4];
#pragma unroll
      for (int jt = 0; jt < 4; jt++) {
        floatx4 a0 = {};
#pragma unroll
        for (int ks = 0; ks < 2; ks++) {
          half8 ak = *reinterpret_cast<half8*>(&Ks[buf][jt * 16 + lr][ks * 32 + lg * 8]);
          a0 = __builtin_amdgcn_mfma_f32_16x16x32_f16(ak, qf[ks], a0, 0, 0, 0);
        }
        s[jt] = a0;
      }
      const int qq = q0 + lr;
#pragma unroll
      for (int jt = 0; jt < 4; jt++)
#pragma unroll
        for (int r = 0; r < 4; r++) {
          float pp = fast_exp2(s[jt][r]);
          if (need_mask) {
            int kv = kvbase + jt * 16 + lg * 4 + r;
            if (kv > qq) pp = 0.f;
          }
          s[jt][r] = pp;
        }
      // P B-fragments straight from registers (k-slot perm):
      half8 pb[2];
#pragma unroll
      for (int ks = 0; ks < 2; ks++) {
#pragma unroll
        for (int e = 0; e < 4; e++) {
          pb[ks][e]     = (half_t)s[2 * ks][e];
          pb[ks][4 + e] = (half_t)s[2 * ks + 1][e];
        }
      }
      // PV: A = V^T fragment, contiguous b128 in the permuted layout
#pragma unroll
      for (int j = 0; j < 5; j++) {
#pragma unroll
        for (int ks = 0; ks < 2; ks++) {
          half8 av = *reinterpret_cast<half8*>(&Vt[buf][j * 16 + lr][ks * 32 + lg * 8]);
          accO[j] = __builtin_amdgcn_mfma_f32_16x16x32_f16(av, pb[ks], accO[j], 0, 0, 0);
        }
      }
    }
    if (t + 1 < t1) {
      WRITET(buf ^ 1);                       // disjoint buffer: no barrier needed first
      __syncthreads();                       // publish buf^1; order reads(buf) < writes(buf)
      buf ^= 1;
    }
  }

  // epilogue: lane holds q = q0+lr, d = j*16 + lg*4 + r -> half4 stores
  half_t* Pw = P + (size_t)split * EOFF;
  float*  Lw = L + (size_t)split * NROW;
  {
    const int q = q0 + lr;
    const size_t rowbase = bh + (size_t)q * DHEAD;
#pragma unroll
    for (int j = 0; j < 4; j++) {
      half4 o;
#pragma unroll
      for (int r = 0; r < 4; r++) o[r] = (half_t)accO[j][r];
      *reinterpret_cast<half4*>(&Pw[rowbase + j * 16 + lg * 4]) = o;
    }
    if (lg == 0)
      Lw[((size_t)b * NH + h) * SEQ + q] = accO[4][0];
  }
#undef LOADT
#undef WRITET
}

// ---------------- combine: O = (P0 + P1) / (l0 + l1), scatter heads -> [B][S][DM] ----
__global__ __launch_bounds__(256) void attn_combine(const half_t* __restrict__ P,
                                                    const float* __restrict__ L,
                                                    half_t* __restrict__ Ab) {
  size_t i = (size_t)blockIdx.x * 256 + threadIdx.x;   // chunk of 8, total E/8
  half8 p0 = *reinterpret_cast<const half8*>(P + i * 8);
  half8 p1 = *reinterpret_cast<const half8*>(P + EOFF + i * 8);
  size_t row = i >> 3;                 // [b][h][s]
  float l = L[row] + L[NROW + row];
  float inv = 1.0f / l;
  int s_ = (int)(row % SEQ);
  int h_ = (int)((row / SEQ) % NH);
  int b_ = (int)(row / ((size_t)SEQ * NH));
  int d0 = (int)(i & 7) * 8;
  half8 o;
#pragma unroll
  for (int e = 0; e < 8; e++)
    o[e] = (half_t)(((float)p0[e] + (float)p1[e]) * inv);
  *reinterpret_cast<half8*>(Ab + ((size_t)b_ * SEQ + s_) * DM + h_ * DHEAD + d0) = o;
}

extern "C" void kernel_launch(void* const* d_in, const int* in_sizes, int n_in,
                              void* d_out, int out_size, void* d_ws, size_t ws_size,
                              hipStream_t stream) {
  const float* q_in = (const float*)d_in[0];
  const float* k_in = (const float*)d_in[1];
  const float* v_in = (const float*)d_in[2];
  const float* Wq   = (const float*)d_in[5];
  const float* Wk   = (const float*)d_in[6];
  const float* Wv   = (const float*)d_in[7];
  const float* Wo   = (const float*)d_in[8];

  const size_t E = EOFF;
  const size_t W = (size_t)DM * DM;
  half_t* ws  = (half_t*)d_ws;
  half_t* Xq  = ws;             // cvt X_q; later: combine output Ab
  half_t* Xk  = ws + E;         // cvt X_k; later: attn partial P (2E)
  half_t* Xv  = ws + 2 * E;
  half_t* Wqh = ws + 3 * E;     // f16 Wq; later: attn partial L (2 x 256KB)
  half_t* Wkh = Wqh + W;
  half_t* Wvh = Wkh + W;
  half_t* Woh = Wvh + W;
  half_t* Qb  = ws + 4 * E;
  half_t* Kb  = ws + 5 * E;
  half_t* Vb  = ws + 6 * E;
  half_t* Ab  = Xq;
  half_t* Pp  = Xk;             // partial O, [2][B][H][S][64]
  float*  Lp  = (float*)Wqh;    // partial sums, [2][NROW]
  if (ws_size < 7 * E * sizeof(half_t)) return;

  cvt_all<<<dim3(2048, 7), 256, 0, stream>>>(q_in, k_in, v_in, Wq, Wk, Wv, Wo,
                                             Xq, Xk, Xv, Wqh, Wkh, Wvh, Woh);
  gemm_qkv<<<768, 256, 0, stream>>>(Xq, Xk, Xv, Wqh, Wkh, Wvh, Qb, Kb, Vb);
  attn_fwd<<<1024, 512, 0, stream>>>(Qb, Kb, Vb, Pp, Lp);
  attn_combine<<<2048, 256, 0, stream>>>(Pp, Lp, Ab);
  gemm_o<<<512, 256, 0, stream>>>(Ab, Woh, (float*)d_out);
}